// Round 2
// baseline (1553.042 us; speedup 1.0000x reference)
//
#include <hip/hip_runtime.h>
#include <math.h>

#define T_TOT 10
#define NB    8
#define NPG   1080
#define NN    (NB*NPG)      // 8640 nodes
#define DEG   16

// ---------------------------------------------------------------------------
// L1 precompute: A[sd][k][h] = dot(W1[k, h*64:(h+1)*64], att_{s,d}[h,:])
__global__ void k_prep_l1(const float* __restrict__ W1, const float* __restrict__ as1,
                          const float* __restrict__ ad1, float* __restrict__ A) {
    int tid = threadIdx.x;
    if (tid >= 32) return;
    int h = tid & 7, k = (tid >> 3) & 1, sd = tid >> 4;
    const float* att = sd ? ad1 : as1;
    float acc = 0.f;
    for (int c = 0; c < 64; ++c) acc += W1[k*512 + h*64 + c] * att[h*64 + c];
    A[sd*16 + k*8 + h] = acc;
}

// e_s/e_d for layer 1 directly from x (rank-2): es[r,h] = x0*A[0][0][h] + x1*A[0][1][h]
__global__ void k_e1(const float* __restrict__ x, const float* __restrict__ A,
                     float* __restrict__ es, float* __restrict__ ed, int R) {
    int r = blockIdx.x*256 + threadIdx.x;
    if (r >= R) return;
    float x0 = x[2*r], x1 = x[2*r+1];
    #pragma unroll
    for (int h = 0; h < 8; ++h) {
        es[r*8+h] = x0*A[h]    + x1*A[8+h];
        ed[r*8+h] = x0*A[16+h] + x1*A[24+h];
    }
}

__device__ __forceinline__ float lrelu(float v) { return v > 0.f ? v : 0.2f*v; }

// Layer-1 fused attention+aggregate+linear+bias+ELU. One 64-lane group per (r, head).
__global__ __launch_bounds__(256) void k_gat1(
    const float* __restrict__ x, const int* __restrict__ esrc,
    const float* __restrict__ es, const float* __restrict__ ed,
    const float* __restrict__ W1, const float* __restrict__ b1,
    float* __restrict__ out, int R) {
    int tid = threadIdx.x;
    int g = blockIdx.x*4 + (tid >> 6);
    int c = tid & 63;
    if (g >= R*8) return;
    int r = g >> 3, hh = g & 7;
    int t = r / NN, n = r - t*NN;
    const int* sp = esrc + n*DEG;
    float edv = ed[r*8 + hh];
    float e_self = lrelu(es[r*8 + hh] + edv);
    float ev[DEG]; int si[DEG];
    float m = e_self;
    #pragma unroll
    for (int j = 0; j < DEG; ++j) {
        int s = sp[j];
        si[j] = t*NN + s;
        float e = lrelu(es[si[j]*8 + hh] + edv);
        ev[j] = e; m = fmaxf(m, e);
    }
    float den = 1e-16f;
    float exs = __expf(e_self - m); den += exs;
    #pragma unroll
    for (int j = 0; j < DEG; ++j) { ev[j] = __expf(ev[j] - m); den += ev[j]; }
    float inv = 1.f / den;
    float xa0 = exs * x[2*r], xa1 = exs * x[2*r+1];
    #pragma unroll
    for (int j = 0; j < DEG; ++j) { xa0 += ev[j]*x[2*si[j]]; xa1 += ev[j]*x[2*si[j]+1]; }
    xa0 *= inv; xa1 *= inv;
    int col = hh*64 + c;
    float v = xa0*W1[col] + xa1*W1[512+col] + b1[col];
    out[(size_t)r*512 + col] = v > 0.f ? v : (__expf(v) - 1.f);
}

// Generic GAT attention+aggregate (+bias+ELU) reading h of width H*C.
template<int H, int C>
__global__ __launch_bounds__(256) void k_gat(
    const float* __restrict__ h, const int* __restrict__ esrc,
    const float* __restrict__ es, const float* __restrict__ ed,
    const float* __restrict__ bias, float* __restrict__ out, int R) {
    constexpr int GPB = 256 / C;
    int tid = threadIdx.x;
    int g = blockIdx.x*GPB + tid / C;
    int c = tid % C;
    if (g >= R*H) return;
    int r = g / H, hh = g % H;
    int t = r / NN, n = r - t*NN;
    const int* sp = esrc + n*DEG;
    float edv = ed[(size_t)r*H + hh];
    float e_self = lrelu(es[(size_t)r*H + hh] + edv);
    float ev[DEG]; int si[DEG];
    float m = e_self;
    #pragma unroll
    for (int j = 0; j < DEG; ++j) {
        int s = sp[j];
        si[j] = t*NN + s;
        float e = lrelu(es[(size_t)si[j]*H + hh] + edv);
        ev[j] = e; m = fmaxf(m, e);
    }
    float den = 1e-16f;
    float exs = __expf(e_self - m); den += exs;
    #pragma unroll
    for (int j = 0; j < DEG; ++j) { ev[j] = __expf(ev[j] - m); den += ev[j]; }
    float inv = 1.f / den;
    constexpr int HC = H*C;
    float acc = exs * h[(size_t)r*HC + hh*C + c];
    #pragma unroll
    for (int j = 0; j < DEG; ++j)
        acc += ev[j] * h[(size_t)si[j]*HC + hh*C + c];
    acc *= inv;
    float v = acc + bias[hh*C + c];
    out[(size_t)r*HC + hh*C + c] = v > 0.f ? v : (__expf(v) - 1.f);
}

// Tiled fp32 GEMM (X[R,K] @ W[K,M]) with fused per-head e_s/e_d epilogue.
// BM=128, BN=128 (grid.y tiles M), BK=8, thread tile 8x8.
__global__ __launch_bounds__(256) void k_gemm_e(
    const float* __restrict__ X, const float* __restrict__ W,
    const float* __restrict__ as_, const float* __restrict__ ad_,
    float* __restrict__ Hout, float* __restrict__ es, float* __restrict__ ed,
    int R, int K, int M, int C) {
    __shared__ float As[8][132];
    __shared__ float Bs[8][132];
    __shared__ float eb[2][128][8];
    int tid = threadIdx.x;
    int tx = tid & 15, ty = tid >> 4;
    int rb = blockIdx.x*128, cb = blockIdx.y*128;
    int HPT = 128 / C;
    for (int i = tid; i < 2*128*8; i += 256) ((float*)eb)[i] = 0.f;
    float acc[8][8] = {};
    int arow = tid >> 1, ak4 = (tid & 1)*4;
    int bk = tid >> 5, bc4 = (tid & 31)*4;
    int arow_c = min(rb + arow, R - 1);
    const float* Xp = X + (size_t)arow_c*K + ak4;
    const float* Wp = W + (size_t)bk*M + cb + bc4;
    for (int kt = 0; kt < K; kt += 8) {
        float4 av = *(const float4*)(Xp + kt);
        float4 bv = *(const float4*)(Wp + (size_t)kt*M);
        __syncthreads();
        As[ak4+0][arow] = av.x; As[ak4+1][arow] = av.y;
        As[ak4+2][arow] = av.z; As[ak4+3][arow] = av.w;
        *(float4*)&Bs[bk][bc4] = bv;
        __syncthreads();
        #pragma unroll
        for (int k = 0; k < 8; ++k) {
            float a[8], b[8];
            #pragma unroll
            for (int i = 0; i < 8; ++i) a[i] = As[k][ty*8 + i];
            #pragma unroll
            for (int j = 0; j < 8; ++j) b[j] = Bs[k][tx*8 + j];
            #pragma unroll
            for (int i = 0; i < 8; ++i)
                #pragma unroll
                for (int j = 0; j < 8; ++j) acc[i][j] += a[i]*b[j];
        }
    }
    #pragma unroll
    for (int i = 0; i < 8; ++i) {
        int r = rb + ty*8 + i;
        if (r < R) {
            *(float4*)&Hout[(size_t)r*M + cb + tx*8]     = make_float4(acc[i][0],acc[i][1],acc[i][2],acc[i][3]);
            *(float4*)&Hout[(size_t)r*M + cb + tx*8 + 4] = make_float4(acc[i][4],acc[i][5],acc[i][6],acc[i][7]);
        }
    }
    int hl = (tx*8)/C, c0 = (tx*8)%C;
    int hg0 = cb / C;
    const float* asp = as_ + (hg0+hl)*C + c0;
    const float* adp = ad_ + (hg0+hl)*C + c0;
    #pragma unroll
    for (int i = 0; i < 8; ++i) {
        float ps = 0.f, pd = 0.f;
        #pragma unroll
        for (int j = 0; j < 8; ++j) { ps += acc[i][j]*asp[j]; pd += acc[i][j]*adp[j]; }
        atomicAdd(&eb[0][ty*8+i][hl], ps);
        atomicAdd(&eb[1][ty*8+i][hl], pd);
    }
    __syncthreads();
    for (int i = tid; i < 128*HPT; i += 256) {
        int row = i / HPT, hh = i % HPT;
        int r = rb + row;
        if (r < R) {
            es[(size_t)r*8 + hg0 + hh] = eb[0][row][hh];
            ed[(size_t)r*8 + hg0 + hh] = eb[1][row][hh];
        }
    }
}

// Layer-4 linear: X[R,128] @ W4[128,8] + e (H=1, C=8). 8 lanes per row.
__global__ __launch_bounds__(256) void k_lin4(
    const float* __restrict__ X, const float* __restrict__ W,
    const float* __restrict__ as_, const float* __restrict__ ad_,
    float* __restrict__ Hout, float* __restrict__ es, float* __restrict__ ed, int R) {
    int tid = threadIdx.x;
    int lane = tid & 63;
    int rl = lane >> 3, cc = lane & 7;
    int r = blockIdx.x*32 + (tid >> 6)*8 + rl;
    if (r >= R) return;
    const float* xp = X + (size_t)r*128;
    float acc = 0.f;
    #pragma unroll 8
    for (int k = 0; k < 128; ++k) acc += xp[k] * W[k*8 + cc];
    Hout[(size_t)r*8 + cc] = acc;
    float ps = acc * as_[cc], pd = acc * ad_[cc];
    #pragma unroll
    for (int off = 4; off >= 1; off >>= 1) {
        ps += __shfl_xor(ps, off, 64);
        pd += __shfl_xor(pd, off, 64);
    }
    if (cc == 0) { es[r] = ps; ed[r] = pd; }
}

// Mean-pool per (t, graph): out4[R,8] -> emb[T,B,8]
__global__ void k_pool(const float* __restrict__ x4, float* __restrict__ emb, int t0) {
    __shared__ float red[256];
    int tl = blockIdx.x >> 3, b = blockIdx.x & 7;
    int tid = threadIdx.x;
    int c = tid & 7, nl = tid >> 3;
    float s = 0.f;
    for (int k = 0; k < 34; ++k) {
        int n = nl + 32*k;
        if (n < NPG) s += x4[((size_t)tl*NN + b*NPG + n)*8 + c];
    }
    red[tid] = s;
    __syncthreads();
    for (int st = 16; st >= 1; st >>= 1) {
        if (nl < st) red[tid] += red[tid + st*8];
        __syncthreads();
    }
    if (nl == 0) emb[((t0 + tl)*8 + b)*8 + c] = red[c] * (1.f/1080.f);
}

// LSTM (one block per batch element) + final FC
__global__ __launch_bounds__(512) void k_lstm(
    const float* __restrict__ emb, const float* __restrict__ w_ih,
    const float* __restrict__ w_hh, const float* __restrict__ b_ih,
    const float* __restrict__ b_hh, const float* __restrict__ w_fc,
    const float* __restrict__ b_fc, float* __restrict__ out) {
    int b = blockIdx.x, u = threadIdx.x;
    __shared__ float h[128], cst[128], g[512];
    if (u < 128) { h[u] = 0.f; cst[u] = 0.f; }
    __syncthreads();
    float bsum = b_ih[u] + b_hh[u];
    for (int t = 0; t < T_TOT; ++t) {
        const float* e = emb + (t*8 + b)*8;
        float acc = bsum;
        #pragma unroll
        for (int k = 0; k < 8; ++k) acc += e[k]*w_ih[u*8 + k];
        for (int k = 0; k < 128; ++k) acc += h[k]*w_hh[u*128 + k];
        g[u] = acc;
        __syncthreads();
        if (u < 128) {
            float ig = 1.f/(1.f + __expf(-g[u]));
            float fg = 1.f/(1.f + __expf(-g[128+u]));
            float gg = tanhf(g[256+u]);
            float og = 1.f/(1.f + __expf(-g[384+u]));
            float cn = fg*cst[u] + ig*gg;
            cst[u] = cn;
            h[u] = og*tanhf(cn);
        }
        __syncthreads();
    }
    if (u < 2) {
        float acc = b_fc[u];
        for (int k = 0; k < 128; ++k) acc += h[k]*w_fc[u*128 + k];
        out[b*2 + u] = acc;
    }
}

extern "C" void kernel_launch(void* const* d_in, const int* in_sizes, int n_in,
                              void* d_out, int out_size, void* d_ws, size_t ws_size,
                              hipStream_t stream) {
    const float* x_seq = (const float*)d_in[0];
    const int*   edge  = (const int*)d_in[1];   // row0 = src
    const float* W1 = (const float*)d_in[3];
    const float* as1 = (const float*)d_in[4];
    const float* ad1 = (const float*)d_in[5];
    const float* b1  = (const float*)d_in[6];
    const float* W2 = (const float*)d_in[7];
    const float* as2 = (const float*)d_in[8];
    const float* ad2 = (const float*)d_in[9];
    const float* b2  = (const float*)d_in[10];
    const float* W3 = (const float*)d_in[11];
    const float* as3 = (const float*)d_in[12];
    const float* ad3 = (const float*)d_in[13];
    const float* b3  = (const float*)d_in[14];
    const float* W4 = (const float*)d_in[15];
    const float* as4 = (const float*)d_in[16];
    const float* ad4 = (const float*)d_in[17];
    const float* b4  = (const float*)d_in[18];
    const float* w_ih = (const float*)d_in[19];
    const float* w_hh = (const float*)d_in[20];
    const float* b_ih = (const float*)d_in[21];
    const float* b_hh = (const float*)d_in[22];
    const float* w_fc = (const float*)d_in[23];
    const float* b_fc = (const float*)d_in[24];

    char* w = (char*)d_ws;
    auto alloc = [&](size_t bytes) {
        char* p = w; w += (bytes + 255) & ~(size_t)255; return (float*)p;
    };
    float* A1  = alloc(128);
    float* emb = alloc((size_t)T_TOT*8*8*4);
    size_t used = (size_t)(w - (char*)d_ws);
    size_t perT = (size_t)NN*(256 + 512 + 8 + 8)*4;  // P + Q + ES + ED per timestep
    size_t rem = (ws_size > used + 4096) ? ws_size - used - 4096 : 0;
    int Tc = (int)(rem / perT);
    if (Tc > T_TOT) Tc = T_TOT;
    if (Tc < 1) Tc = 1;
    float* P  = alloc((size_t)Tc*NN*256*4);
    float* ES = alloc((size_t)Tc*NN*8*4);
    float* ED = alloc((size_t)Tc*NN*8*4);
    float* Q  = alloc((size_t)Tc*NN*512*4);

    k_prep_l1<<<1, 64, 0, stream>>>(W1, as1, ad1, A1);
    for (int t0 = 0; t0 < T_TOT; t0 += Tc) {
        int tc = (Tc < T_TOT - t0) ? Tc : (T_TOT - t0);
        int R = tc*NN;
        const float* xoff = x_seq + (size_t)t0*NN*2;
        // Layer 1 (rank-2 shortcut)
        k_e1<<<(R + 255)/256, 256, 0, stream>>>(xoff, A1, ES, ED, R);
        k_gat1<<<R*2, 256, 0, stream>>>(xoff, edge, ES, ED, W1, b1, Q, R);
        // Layer 2
        k_gemm_e<<<dim3((R + 127)/128, 2), 256, 0, stream>>>(Q, W2, as2, ad2, P, ES, ED, R, 512, 256, 32);
        k_gat<8,32><<<R, 256, 0, stream>>>(P, edge, ES, ED, b2, Q, R);
        // Layer 3
        k_gemm_e<<<dim3((R + 127)/128, 1), 256, 0, stream>>>(Q, W3, as3, ad3, P, ES, ED, R, 256, 128, 16);
        k_gat<8,16><<<R/2, 256, 0, stream>>>(P, edge, ES, ED, b3, Q, R);
        // Layer 4
        k_lin4<<<R/32, 256, 0, stream>>>(Q, W4, as4, ad4, P, ES, ED, R);
        k_gat<1,8><<<R/32, 256, 0, stream>>>(P, edge, ES, ED, b4, Q, R);
        // Pool
        k_pool<<<tc*8, 256, 0, stream>>>(Q, emb, t0);
    }
    k_lstm<<<8, 512, 0, stream>>>(emb, w_ih, w_hh, b_ih, b_hh, w_fc, b_fc, (float*)d_out);
}

// Round 3
// 983.180 us; speedup vs baseline: 1.5796x; 1.5796x over previous
//
#include <hip/hip_runtime.h>
#include <math.h>

#define T_TOT 10
#define NB    8
#define NPG   1080
#define NN    (NB*NPG)      // 8640 nodes
#define DEG   16

__device__ __forceinline__ float lrelu(float v) { return v > 0.f ? v : 0.2f*v; }
__device__ __forceinline__ float elu1(float v)  { return v > 0.f ? v : (__expf(v) - 1.f); }

// ---------------------------------------------------------------------------
// L1 precompute: A[sd][k][h] = dot(W1[k, h*64:(h+1)*64], att_{s,d}[h,:])
__global__ void k_prep_l1(const float* __restrict__ W1, const float* __restrict__ as1,
                          const float* __restrict__ ad1, float* __restrict__ A) {
    int tid = threadIdx.x;
    if (tid >= 32) return;
    int h = tid & 7, k = (tid >> 3) & 1, sd = tid >> 4;
    const float* att = sd ? ad1 : as1;
    float acc = 0.f;
    for (int c = 0; c < 64; ++c) acc += W1[k*512 + h*64 + c] * att[h*64 + c];
    A[sd*16 + k*8 + h] = acc;
}

// e_s/e_d for layer 1 directly from x (rank-2)
__global__ void k_e1(const float* __restrict__ x, const float* __restrict__ A,
                     float* __restrict__ es, float* __restrict__ ed, int R) {
    int r = blockIdx.x*256 + threadIdx.x;
    if (r >= R) return;
    float x0 = x[2*r], x1 = x[2*r+1];
    #pragma unroll
    for (int h = 0; h < 8; ++h) {
        es[r*8+h] = x0*A[h]    + x1*A[8+h];
        ed[r*8+h] = x0*A[16+h] + x1*A[24+h];
    }
}

// Layer-1 fused attention+aggregate+linear+bias+ELU.
// Cooperative softmax: 16 lanes per (r,head); lane l owns edge l (+self on l==0).
// Rank-2 shortcut: aggregate x (2 scalars), expand through W1 with float4 stores.
__global__ __launch_bounds__(256) void k_gat1(
    const float* __restrict__ x, const int* __restrict__ esrc,
    const float* __restrict__ es, const float* __restrict__ ed,
    const float* __restrict__ W1, const float* __restrict__ b1,
    float* __restrict__ out, int R) {
    int tid = threadIdx.x;
    int g = blockIdx.x*16 + (tid >> 4);       // group = r*8 + hh
    int l = tid & 15;
    if (g >= R*8) g = R*8 - 1;                // benign duplicate of last group
    int r = g >> 3, hh = g & 7;
    int t = r / NN, n = r - t*NN;
    float edv = ed[r*8 + hh];
    int s0 = t*NN + esrc[n*DEG + l];
    float e0 = lrelu(es[s0*8 + hh] + edv);
    float e1 = (l == 0) ? lrelu(es[r*8 + hh] + edv) : -1e30f;
    float m = fmaxf(e0, e1);
    #pragma unroll
    for (int off = 8; off >= 1; off >>= 1) m = fmaxf(m, __shfl_xor(m, off, 16));
    float ex0 = __expf(e0 - m);
    float ex1 = (l == 0) ? __expf(e1 - m) : 0.f;
    float den = ex0 + ex1;
    float p0 = ex0*x[2*s0]   + ex1*x[2*r];
    float p1 = ex0*x[2*s0+1] + ex1*x[2*r+1];
    #pragma unroll
    for (int off = 8; off >= 1; off >>= 1) {
        den += __shfl_xor(den, off, 16);
        p0  += __shfl_xor(p0,  off, 16);
        p1  += __shfl_xor(p1,  off, 16);
    }
    float inv = 1.f/(den + 1e-16f);
    float xa0 = p0*inv, xa1 = p1*inv;
    int col = hh*64 + l*4;
    float4 w0 = *(const float4*)&W1[col];
    float4 w1 = *(const float4*)&W1[512 + col];
    float4 bb = *(const float4*)&b1[col];
    float4 v;
    v.x = elu1(xa0*w0.x + xa1*w1.x + bb.x);
    v.y = elu1(xa0*w0.y + xa1*w1.y + bb.y);
    v.z = elu1(xa0*w0.z + xa1*w1.z + bb.z);
    v.w = elu1(xa0*w0.w + xa1*w1.w + bb.w);
    *(float4*)&out[(size_t)r*512 + col] = v;
}

// Generic GAT attention+aggregate (+bias+ELU).
// LANES=C/4 lanes per (r,head); cooperative softmax; weights+indices staged in
// LDS (stride 17, odd -> conflict-free broadcast); float4 gathers/stores.
template<int H, int C>
__global__ __launch_bounds__(256) void k_gat(
    const float* __restrict__ hb, const int* __restrict__ esrc,
    const float* __restrict__ es, const float* __restrict__ ed,
    const float* __restrict__ bias, float* __restrict__ out, int R) {
    constexpr int LANES = C/4;
    constexpr int GPB = 256/LANES;
    constexpr int EPL = (17 + LANES - 1)/LANES;
    __shared__ float wsm[GPB][17];
    __shared__ int   ssm[GPB][17];
    int tid = threadIdx.x;
    int grp = tid / LANES;
    int l = tid % LANES;
    int g = blockIdx.x*GPB + grp;             // group = r*H + hh
    if (g >= R*H) g = R*H - 1;                // benign duplicate (no barrier hang)
    int r = g / H, hh = g % H;
    int t = r / NN, n = r - t*NN;
    float edv = ed[(size_t)r*H + hh];
    float ev[EPL]; int sv[EPL];
    float m = -1e30f;
    #pragma unroll
    for (int s = 0; s < EPL; ++s) {
        int j = s*LANES + l;
        if (j < 17) {
            int src = (j == 16) ? r : (t*NN + esrc[n*DEG + j]);
            sv[s] = src;
            float e = lrelu(es[(size_t)src*H + hh] + edv);
            ev[s] = e; m = fmaxf(m, e);
        } else { ev[s] = -1e30f; sv[s] = r; }
    }
    #pragma unroll
    for (int off = LANES/2; off >= 1; off >>= 1) m = fmaxf(m, __shfl_xor(m, off, LANES));
    float den = 0.f;
    #pragma unroll
    for (int s = 0; s < EPL; ++s) {
        int j = s*LANES + l;
        float e2 = (j < 17) ? __expf(ev[s] - m) : 0.f;
        ev[s] = e2; den += e2;
    }
    #pragma unroll
    for (int off = LANES/2; off >= 1; off >>= 1) den += __shfl_xor(den, off, LANES);
    float inv = 1.f/(den + 1e-16f);
    #pragma unroll
    for (int s = 0; s < EPL; ++s) {
        int j = s*LANES + l;
        if (j < 17) { wsm[grp][j] = ev[s]*inv; ssm[grp][j] = sv[s]; }
    }
    __syncthreads();
    constexpr int HC = H*C;
    int base = hh*C + l*4;
    float ax = 0.f, ay = 0.f, az = 0.f, aw = 0.f;
    #pragma unroll
    for (int j = 0; j < 17; ++j) {
        float wj = wsm[grp][j];
        float4 hv = *(const float4*)&hb[(size_t)ssm[grp][j]*HC + base];
        ax += wj*hv.x; ay += wj*hv.y; az += wj*hv.z; aw += wj*hv.w;
    }
    float4 bb = *(const float4*)&bias[base];
    float4 v;
    v.x = elu1(ax + bb.x);
    v.y = elu1(ay + bb.y);
    v.z = elu1(az + bb.z);
    v.w = elu1(aw + bb.w);
    *(float4*)&out[(size_t)r*HC + base] = v;
}

// Tiled fp32 GEMM (X[R,K] @ W[K,M]) with fused per-head e_s/e_d epilogue.
__global__ __launch_bounds__(256) void k_gemm_e(
    const float* __restrict__ X, const float* __restrict__ W,
    const float* __restrict__ as_, const float* __restrict__ ad_,
    float* __restrict__ Hout, float* __restrict__ es, float* __restrict__ ed,
    int R, int K, int M, int C) {
    __shared__ float As[8][132];
    __shared__ float Bs[8][132];
    __shared__ float eb[2][128][8];
    int tid = threadIdx.x;
    int tx = tid & 15, ty = tid >> 4;
    int rb = blockIdx.x*128, cb = blockIdx.y*128;
    int HPT = 128 / C;
    for (int i = tid; i < 2*128*8; i += 256) ((float*)eb)[i] = 0.f;
    float acc[8][8] = {};
    int arow = tid >> 1, ak4 = (tid & 1)*4;
    int bk = tid >> 5, bc4 = (tid & 31)*4;
    int arow_c = min(rb + arow, R - 1);
    const float* Xp = X + (size_t)arow_c*K + ak4;
    const float* Wp = W + (size_t)bk*M + cb + bc4;
    for (int kt = 0; kt < K; kt += 8) {
        float4 av = *(const float4*)(Xp + kt);
        float4 bv = *(const float4*)(Wp + (size_t)kt*M);
        __syncthreads();
        As[ak4+0][arow] = av.x; As[ak4+1][arow] = av.y;
        As[ak4+2][arow] = av.z; As[ak4+3][arow] = av.w;
        *(float4*)&Bs[bk][bc4] = bv;
        __syncthreads();
        #pragma unroll
        for (int k = 0; k < 8; ++k) {
            float a[8], b[8];
            #pragma unroll
            for (int i = 0; i < 8; ++i) a[i] = As[k][ty*8 + i];
            #pragma unroll
            for (int j = 0; j < 8; ++j) b[j] = Bs[k][tx*8 + j];
            #pragma unroll
            for (int i = 0; i < 8; ++i)
                #pragma unroll
                for (int j = 0; j < 8; ++j) acc[i][j] += a[i]*b[j];
        }
    }
    #pragma unroll
    for (int i = 0; i < 8; ++i) {
        int r = rb + ty*8 + i;
        if (r < R) {
            *(float4*)&Hout[(size_t)r*M + cb + tx*8]     = make_float4(acc[i][0],acc[i][1],acc[i][2],acc[i][3]);
            *(float4*)&Hout[(size_t)r*M + cb + tx*8 + 4] = make_float4(acc[i][4],acc[i][5],acc[i][6],acc[i][7]);
        }
    }
    int hl = (tx*8)/C, c0 = (tx*8)%C;
    int hg0 = cb / C;
    const float* asp = as_ + (hg0+hl)*C + c0;
    const float* adp = ad_ + (hg0+hl)*C + c0;
    #pragma unroll
    for (int i = 0; i < 8; ++i) {
        float ps = 0.f, pd = 0.f;
        #pragma unroll
        for (int j = 0; j < 8; ++j) { ps += acc[i][j]*asp[j]; pd += acc[i][j]*adp[j]; }
        atomicAdd(&eb[0][ty*8+i][hl], ps);
        atomicAdd(&eb[1][ty*8+i][hl], pd);
    }
    __syncthreads();
    for (int i = tid; i < 128*HPT; i += 256) {
        int row = i / HPT, hh = i % HPT;
        int r = rb + row;
        if (r < R) {
            es[(size_t)r*8 + hg0 + hh] = eb[0][row][hh];
            ed[(size_t)r*8 + hg0 + hh] = eb[1][row][hh];
        }
    }
}

// Layer-4 linear: X[R,128] @ W4[128,8] + e (H=1, C=8). 8 lanes per row.
__global__ __launch_bounds__(256) void k_lin4(
    const float* __restrict__ X, const float* __restrict__ W,
    const float* __restrict__ as_, const float* __restrict__ ad_,
    float* __restrict__ Hout, float* __restrict__ es, float* __restrict__ ed, int R) {
    int tid = threadIdx.x;
    int lane = tid & 63;
    int rl = lane >> 3, cc = lane & 7;
    int r = blockIdx.x*32 + (tid >> 6)*8 + rl;
    if (r >= R) return;
    const float* xp = X + (size_t)r*128;
    float acc = 0.f;
    #pragma unroll 8
    for (int k = 0; k < 128; ++k) acc += xp[k] * W[k*8 + cc];
    Hout[(size_t)r*8 + cc] = acc;
    float ps = acc * as_[cc], pd = acc * ad_[cc];
    #pragma unroll
    for (int off = 4; off >= 1; off >>= 1) {
        ps += __shfl_xor(ps, off, 64);
        pd += __shfl_xor(pd, off, 64);
    }
    if (cc == 0) { es[r] = ps; ed[r] = pd; }
}

// Mean-pool per (t, graph): out4[R,8] -> emb[T,B,8]
__global__ void k_pool(const float* __restrict__ x4, float* __restrict__ emb, int t0) {
    __shared__ float red[256];
    int tl = blockIdx.x >> 3, b = blockIdx.x & 7;
    int tid = threadIdx.x;
    int c = tid & 7, nl = tid >> 3;
    float s = 0.f;
    for (int k = 0; k < 34; ++k) {
        int n = nl + 32*k;
        if (n < NPG) s += x4[((size_t)tl*NN + b*NPG + n)*8 + c];
    }
    red[tid] = s;
    __syncthreads();
    for (int st = 16; st >= 1; st >>= 1) {
        if (nl < st) red[tid] += red[tid + st*8];
        __syncthreads();
    }
    if (nl == 0) emb[((t0 + tl)*8 + b)*8 + c] = red[c] * (1.f/1080.f);
}

// LSTM (one block per batch element) + final FC
__global__ __launch_bounds__(512) void k_lstm(
    const float* __restrict__ emb, const float* __restrict__ w_ih,
    const float* __restrict__ w_hh, const float* __restrict__ b_ih,
    const float* __restrict__ b_hh, const float* __restrict__ w_fc,
    const float* __restrict__ b_fc, float* __restrict__ out) {
    int b = blockIdx.x, u = threadIdx.x;
    __shared__ float h[128], cst[128], g[512];
    if (u < 128) { h[u] = 0.f; cst[u] = 0.f; }
    __syncthreads();
    float bsum = b_ih[u] + b_hh[u];
    for (int t = 0; t < T_TOT; ++t) {
        const float* e = emb + (t*8 + b)*8;
        float acc = bsum;
        #pragma unroll
        for (int k = 0; k < 8; ++k) acc += e[k]*w_ih[u*8 + k];
        for (int k = 0; k < 128; ++k) acc += h[k]*w_hh[u*128 + k];
        g[u] = acc;
        __syncthreads();
        if (u < 128) {
            float ig = 1.f/(1.f + __expf(-g[u]));
            float fg = 1.f/(1.f + __expf(-g[128+u]));
            float gg = tanhf(g[256+u]);
            float og = 1.f/(1.f + __expf(-g[384+u]));
            float cn = fg*cst[u] + ig*gg;
            cst[u] = cn;
            h[u] = og*tanhf(cn);
        }
        __syncthreads();
    }
    if (u < 2) {
        float acc = b_fc[u];
        for (int k = 0; k < 128; ++k) acc += h[k]*w_fc[u*128 + k];
        out[b*2 + u] = acc;
    }
}

extern "C" void kernel_launch(void* const* d_in, const int* in_sizes, int n_in,
                              void* d_out, int out_size, void* d_ws, size_t ws_size,
                              hipStream_t stream) {
    const float* x_seq = (const float*)d_in[0];
    const int*   edge  = (const int*)d_in[1];   // row0 = src
    const float* W1 = (const float*)d_in[3];
    const float* as1 = (const float*)d_in[4];
    const float* ad1 = (const float*)d_in[5];
    const float* b1  = (const float*)d_in[6];
    const float* W2 = (const float*)d_in[7];
    const float* as2 = (const float*)d_in[8];
    const float* ad2 = (const float*)d_in[9];
    const float* b2  = (const float*)d_in[10];
    const float* W3 = (const float*)d_in[11];
    const float* as3 = (const float*)d_in[12];
    const float* ad3 = (const float*)d_in[13];
    const float* b3  = (const float*)d_in[14];
    const float* W4 = (const float*)d_in[15];
    const float* as4 = (const float*)d_in[16];
    const float* ad4 = (const float*)d_in[17];
    const float* b4  = (const float*)d_in[18];
    const float* w_ih = (const float*)d_in[19];
    const float* w_hh = (const float*)d_in[20];
    const float* b_ih = (const float*)d_in[21];
    const float* b_hh = (const float*)d_in[22];
    const float* w_fc = (const float*)d_in[23];
    const float* b_fc = (const float*)d_in[24];

    char* w = (char*)d_ws;
    auto alloc = [&](size_t bytes) {
        char* p = w; w += (bytes + 255) & ~(size_t)255; return (float*)p;
    };
    float* A1  = alloc(128);
    float* emb = alloc((size_t)T_TOT*8*8*4);
    size_t used = (size_t)(w - (char*)d_ws);
    size_t perT = (size_t)NN*(256 + 512 + 8 + 8)*4;  // P + Q + ES + ED per timestep
    size_t rem = (ws_size > used + 4096) ? ws_size - used - 4096 : 0;
    int Tc = (int)(rem / perT);
    if (Tc > T_TOT) Tc = T_TOT;
    if (Tc < 1) Tc = 1;
    float* P  = alloc((size_t)Tc*NN*256*4);
    float* ES = alloc((size_t)Tc*NN*8*4);
    float* ED = alloc((size_t)Tc*NN*8*4);
    float* Q  = alloc((size_t)Tc*NN*512*4);

    k_prep_l1<<<1, 64, 0, stream>>>(W1, as1, ad1, A1);
    for (int t0 = 0; t0 < T_TOT; t0 += Tc) {
        int tc = (Tc < T_TOT - t0) ? Tc : (T_TOT - t0);
        int R = tc*NN;
        const float* xoff = x_seq + (size_t)t0*NN*2;
        // Layer 1 (rank-2 shortcut, cooperative softmax)
        k_e1<<<(R + 255)/256, 256, 0, stream>>>(xoff, A1, ES, ED, R);
        k_gat1<<<(R*8 + 15)/16, 256, 0, stream>>>(xoff, edge, ES, ED, W1, b1, Q, R);
        // Layer 2: GEMM 512->256 (+e), then agg (H=8, C=32, LANES=8, GPB=32)
        k_gemm_e<<<dim3((R + 127)/128, 2), 256, 0, stream>>>(Q, W2, as2, ad2, P, ES, ED, R, 512, 256, 32);
        k_gat<8,32><<<(R*8 + 31)/32, 256, 0, stream>>>(P, edge, ES, ED, b2, Q, R);
        // Layer 3: GEMM 256->128 (+e), then agg (H=8, C=16, LANES=4, GPB=64)
        k_gemm_e<<<dim3((R + 127)/128, 1), 256, 0, stream>>>(Q, W3, as3, ad3, P, ES, ED, R, 256, 128, 16);
        k_gat<8,16><<<(R*8 + 63)/64, 256, 0, stream>>>(P, edge, ES, ED, b3, Q, R);
        // Layer 4: linear 128->8 (+e), then agg (H=1, C=8, LANES=2, GPB=128)
        k_lin4<<<R/32, 256, 0, stream>>>(Q, W4, as4, ad4, P, ES, ED, R);
        k_gat<1,8><<<(R + 127)/128, 256, 0, stream>>>(P, edge, ES, ED, b4, Q, R);
        // Pool
        k_pool<<<tc*8, 256, 0, stream>>>(Q, emb, t0);
    }
    k_lstm<<<8, 512, 0, stream>>>(emb, w_ih, w_hh, b_ih, b_hh, w_fc, b_fc, (float*)d_out);
}

// Round 4
// 651.646 us; speedup vs baseline: 2.3833x; 1.5088x over previous
//
#include <hip/hip_runtime.h>
#include <math.h>

#define T_TOT 10
#define NB    8
#define NPG   1080
#define NN    (NB*NPG)      // 8640 nodes
#define DEG   16

typedef unsigned short ushortT;
using short8 = __attribute__((ext_vector_type(8))) short;
using f32x4  = __attribute__((ext_vector_type(4))) float;

__device__ __forceinline__ float lrelu(float v) { return v > 0.f ? v : 0.2f*v; }
__device__ __forceinline__ float elu1(float v)  { return v > 0.f ? v : (__expf(v) - 1.f); }
__device__ __forceinline__ ushortT bhi(float v) { return (ushortT)(__float_as_uint(v) >> 16); }
__device__ __forceinline__ float bf2f(ushortT h){ return __uint_as_float(((unsigned)h) << 16); }

// ---------------------------------------------------------------------------
// L1 precompute: A[sd][k][h] = dot(W1[k, h*64:(h+1)*64], att_{s,d}[h,:])
__global__ void k_prep_l1(const float* __restrict__ W1, const float* __restrict__ as1,
                          const float* __restrict__ ad1, float* __restrict__ A) {
    int tid = threadIdx.x;
    if (tid >= 32) return;
    int h = tid & 7, k = (tid >> 3) & 1, sd = tid >> 4;
    const float* att = sd ? ad1 : as1;
    float acc = 0.f;
    for (int c = 0; c < 64; ++c) acc += W1[k*512 + h*64 + c] * att[h*64 + c];
    A[sd*16 + k*8 + h] = acc;
}

// W [K,M] fp32 -> WT [M,K] bf16 (RNE)
__global__ void k_prepW(const float* __restrict__ W, ushortT* __restrict__ WT, int K, int M) {
    int i = blockIdx.x*256 + threadIdx.x;
    if (i >= K*M) return;
    int k = i / M, m = i - k*M;
    unsigned u = __float_as_uint(W[i]);
    u += 0x7FFFu + ((u >> 16) & 1u);
    WT[(size_t)m*K + k] = (ushortT)(u >> 16);
}

// e_s/e_d for layer 1 directly from x (rank-2)
__global__ void k_e1(const float* __restrict__ x, const float* __restrict__ A,
                     float* __restrict__ es, float* __restrict__ ed, int R) {
    int r = blockIdx.x*256 + threadIdx.x;
    if (r >= R) return;
    float x0 = x[2*r], x1 = x[2*r+1];
    #pragma unroll
    for (int h = 0; h < 8; ++h) {
        es[r*8+h] = x0*A[h]    + x1*A[8+h];
        ed[r*8+h] = x0*A[16+h] + x1*A[24+h];
    }
}

// Layer-1 fused attention+aggregate+linear+bias+ELU -> bf16 hi/lo planes.
__global__ __launch_bounds__(256) void k_gat1(
    const float* __restrict__ x, const int* __restrict__ esrc,
    const float* __restrict__ es, const float* __restrict__ ed,
    const float* __restrict__ W1, const float* __restrict__ b1,
    ushortT* __restrict__ qhi, ushortT* __restrict__ qlo, int R) {
    int tid = threadIdx.x;
    int g = blockIdx.x*16 + (tid >> 4);       // group = r*8 + hh
    int l = tid & 15;
    if (g >= R*8) g = R*8 - 1;
    int r = g >> 3, hh = g & 7;
    int t = r / NN, n = r - t*NN;
    float edv = ed[r*8 + hh];
    int s0 = t*NN + esrc[n*DEG + l];
    float e0 = lrelu(es[s0*8 + hh] + edv);
    float e1 = (l == 0) ? lrelu(es[r*8 + hh] + edv) : -1e30f;
    float m = fmaxf(e0, e1);
    #pragma unroll
    for (int off = 8; off >= 1; off >>= 1) m = fmaxf(m, __shfl_xor(m, off, 16));
    float ex0 = __expf(e0 - m);
    float ex1 = (l == 0) ? __expf(e1 - m) : 0.f;
    float den = ex0 + ex1;
    float p0 = ex0*x[2*s0]   + ex1*x[2*r];
    float p1 = ex0*x[2*s0+1] + ex1*x[2*r+1];
    #pragma unroll
    for (int off = 8; off >= 1; off >>= 1) {
        den += __shfl_xor(den, off, 16);
        p0  += __shfl_xor(p0,  off, 16);
        p1  += __shfl_xor(p1,  off, 16);
    }
    float inv = 1.f/(den + 1e-16f);
    float xa0 = p0*inv, xa1 = p1*inv;
    int col = hh*64 + l*4;
    float4 w0 = *(const float4*)&W1[col];
    float4 w1 = *(const float4*)&W1[512 + col];
    float4 bb = *(const float4*)&b1[col];
    float4 v;
    v.x = elu1(xa0*w0.x + xa1*w1.x + bb.x);
    v.y = elu1(xa0*w0.y + xa1*w1.y + bb.y);
    v.z = elu1(xa0*w0.z + xa1*w1.z + bb.z);
    v.w = elu1(xa0*w0.w + xa1*w1.w + bb.w);
    ushort4 h4, l4;
    h4.x = bhi(v.x); l4.x = bhi(v.x - bf2f(h4.x));
    h4.y = bhi(v.y); l4.y = bhi(v.y - bf2f(h4.y));
    h4.z = bhi(v.z); l4.z = bhi(v.z - bf2f(h4.z));
    h4.w = bhi(v.w); l4.w = bhi(v.w - bf2f(h4.w));
    *(ushort4*)&qhi[(size_t)r*512 + col] = h4;
    *(ushort4*)&qlo[(size_t)r*512 + col] = l4;
}

// Generic GAT attention+aggregate (+bias+ELU); optional bf16 hi/lo output.
template<int H, int C, bool BF16OUT>
__global__ __launch_bounds__(256) void k_gat(
    const float* __restrict__ hb, const int* __restrict__ esrc,
    const float* __restrict__ es, const float* __restrict__ ed,
    const float* __restrict__ bias, float* __restrict__ out,
    ushortT* __restrict__ ohi, ushortT* __restrict__ olo, int R) {
    constexpr int LANES = C/4;
    constexpr int GPB = 256/LANES;
    constexpr int EPL = (17 + LANES - 1)/LANES;
    __shared__ float wsm[GPB][17];
    __shared__ int   ssm[GPB][17];
    int tid = threadIdx.x;
    int grp = tid / LANES;
    int l = tid % LANES;
    int g = blockIdx.x*GPB + grp;             // group = r*H + hh
    if (g >= R*H) g = R*H - 1;
    int r = g / H, hh = g % H;
    int t = r / NN, n = r - t*NN;
    float edv = ed[(size_t)r*H + hh];
    float ev[EPL]; int sv[EPL];
    float m = -1e30f;
    #pragma unroll
    for (int s = 0; s < EPL; ++s) {
        int j = s*LANES + l;
        if (j < 17) {
            int src = (j == 16) ? r : (t*NN + esrc[n*DEG + j]);
            sv[s] = src;
            float e = lrelu(es[(size_t)src*H + hh] + edv);
            ev[s] = e; m = fmaxf(m, e);
        } else { ev[s] = -1e30f; sv[s] = r; }
    }
    #pragma unroll
    for (int off = LANES/2; off >= 1; off >>= 1) m = fmaxf(m, __shfl_xor(m, off, LANES));
    float den = 0.f;
    #pragma unroll
    for (int s = 0; s < EPL; ++s) {
        int j = s*LANES + l;
        float e2 = (j < 17) ? __expf(ev[s] - m) : 0.f;
        ev[s] = e2; den += e2;
    }
    #pragma unroll
    for (int off = LANES/2; off >= 1; off >>= 1) den += __shfl_xor(den, off, LANES);
    float inv = 1.f/(den + 1e-16f);
    #pragma unroll
    for (int s = 0; s < EPL; ++s) {
        int j = s*LANES + l;
        if (j < 17) { wsm[grp][j] = ev[s]*inv; ssm[grp][j] = sv[s]; }
    }
    __syncthreads();
    constexpr int HC = H*C;
    int base = hh*C + l*4;
    float ax = 0.f, ay = 0.f, az = 0.f, aw = 0.f;
    #pragma unroll
    for (int j = 0; j < 17; ++j) {
        float wj = wsm[grp][j];
        float4 hv = *(const float4*)&hb[(size_t)ssm[grp][j]*HC + base];
        ax += wj*hv.x; ay += wj*hv.y; az += wj*hv.z; aw += wj*hv.w;
    }
    float4 bb = *(const float4*)&bias[base];
    float4 v;
    v.x = elu1(ax + bb.x);
    v.y = elu1(ay + bb.y);
    v.z = elu1(az + bb.z);
    v.w = elu1(aw + bb.w);
    if constexpr (BF16OUT) {
        ushort4 h4, l4;
        h4.x = bhi(v.x); l4.x = bhi(v.x - bf2f(h4.x));
        h4.y = bhi(v.y); l4.y = bhi(v.y - bf2f(h4.y));
        h4.z = bhi(v.z); l4.z = bhi(v.z - bf2f(h4.z));
        h4.w = bhi(v.w); l4.w = bhi(v.w - bf2f(h4.w));
        *(ushort4*)&ohi[(size_t)r*HC + base] = h4;
        *(ushort4*)&olo[(size_t)r*HC + base] = l4;
    } else {
        *(float4*)&out[(size_t)r*HC + base] = v;
    }
}

// MFMA GEMM: Hout[R,M] = X[R,K] @ W[K,M], X = (Xhi + Xlo) bf16 planes, W = WT[M,K] bf16.
// 128x128 tile, 4 waves 2x2 (64x64 each, 4x4 frags of 16x16x32), BK=64.
// Fused es/ed epilogue (per-head dot with as_/ad_, C channels/head).
template<int C>
__global__ __launch_bounds__(256) void k_gemm_mfma(
    const ushortT* __restrict__ Xhi, const ushortT* __restrict__ Xlo,
    const ushortT* __restrict__ WT,
    const float* __restrict__ as_, const float* __restrict__ ad_,
    float* __restrict__ Hout, float* __restrict__ es, float* __restrict__ ed,
    int R, int K, int M) {
    __shared__ __align__(16) char smem[49152];   // Ahi 16K | Alo 16K | B 16K
    int tid = threadIdx.x;
    int wid = tid >> 6, l = tid & 63;
    int l15 = l & 15, lg = l >> 4;
    int wr = wid >> 1, wc = wid & 1;
    int rb = blockIdx.x*128, cb = blockIdx.y*128;

    f32x4 acc[4][4] = {};
    int aoff[4], asw[4], boff[4], bsw[4];
    #pragma unroll
    for (int i = 0; i < 4; ++i) {
        int ar = wr*64 + i*16 + l15;
        aoff[i] = ar*128; asw[i] = (ar & 7) << 4;
        int bc = wc*64 + i*16 + l15;
        boff[i] = 32768 + bc*128; bsw[i] = (bc & 7) << 4;
    }
    int kb0 = lg*16;
    const size_t strideB = (size_t)K*2;
    int srow = tid >> 3, sc8 = tid & 7;      // staging: 4 row-strides of 32
    int ssw = ((srow & 7) << 4);
    const int nKT = K >> 6;

    for (int kt = 0; kt < nKT; ++kt) {
        int kbyte = kt*128;
        __syncthreads();
        #pragma unroll
        for (int i = 0; i < 4; ++i) {
            int row = srow + i*32;
            int dst = row*128 + ((sc8*16) ^ ssw);
            int rg = min(rb + row, R - 1);
            uint4 va = *(const uint4*)((const char*)Xhi + (size_t)rg*strideB + kbyte + sc8*16);
            uint4 vl = *(const uint4*)((const char*)Xlo + (size_t)rg*strideB + kbyte + sc8*16);
            uint4 vw = *(const uint4*)((const char*)WT  + (size_t)(cb + row)*strideB + kbyte + sc8*16);
            *(uint4*)(smem + dst)         = va;
            *(uint4*)(smem + 16384 + dst) = vl;
            *(uint4*)(smem + 32768 + dst) = vw;
        }
        __syncthreads();
        #pragma unroll
        for (int ks = 0; ks < 2; ++ks) {
            int kb = ks*64 + kb0;
            short8 ah[4], al[4], bv[4];
            #pragma unroll
            for (int i = 0; i < 4; ++i) {
                ah[i] = *(const short8*)(smem + aoff[i] + (kb ^ asw[i]));
                al[i] = *(const short8*)(smem + 16384 + aoff[i] + (kb ^ asw[i]));
                bv[i] = *(const short8*)(smem + boff[i] + (kb ^ bsw[i]));
            }
            #pragma unroll
            for (int mt = 0; mt < 4; ++mt)
                #pragma unroll
                for (int nt = 0; nt < 4; ++nt) {
                    acc[mt][nt] = __builtin_amdgcn_mfma_f32_16x16x32_bf16(ah[mt], bv[nt], acc[mt][nt], 0, 0, 0);
                    acc[mt][nt] = __builtin_amdgcn_mfma_f32_16x16x32_bf16(al[mt], bv[nt], acc[mt][nt], 0, 0, 0);
                }
        }
    }
    __syncthreads();
    // epilogue: es/ed per head + C store
    constexpr int NSL = 128/C;               // head slots per block
    constexpr int NHW = 64/C;                // head slots per wave
    int hg0 = cb / C;
    float asv[4], adv[4];
    #pragma unroll
    for (int nt = 0; nt < 4; ++nt) {
        int col = wc*64 + nt*16 + l15;
        int h = col / C, c = col - h*C;
        asv[nt] = as_[(hg0 + h)*C + c];
        adv[nt] = ad_[(hg0 + h)*C + c];
    }
    float* ebp = (float*)smem;               // [128][NSL][2]
    #pragma unroll
    for (int mt = 0; mt < 4; ++mt) {
        float ps[4][NHW] = {}, pd[4][NHW] = {};
        #pragma unroll
        for (int nt = 0; nt < 4; ++nt) {
            constexpr int dv = 16;
            int sl = (nt*dv)/C;
            #pragma unroll
            for (int q = 0; q < 4; ++q) {
                ps[q][sl] += acc[mt][nt][q]*asv[nt];
                pd[q][sl] += acc[mt][nt][q]*adv[nt];
            }
        }
        #pragma unroll
        for (int off = 1; off < 16; off <<= 1)
            #pragma unroll
            for (int q = 0; q < 4; ++q)
                #pragma unroll
                for (int sl = 0; sl < NHW; ++sl) {
                    ps[q][sl] += __shfl_xor(ps[q][sl], off);
                    pd[q][sl] += __shfl_xor(pd[q][sl], off);
                }
        if (l15 == 0) {
            #pragma unroll
            for (int q = 0; q < 4; ++q) {
                int row = wr*64 + mt*16 + lg*4 + q;
                #pragma unroll
                for (int sl = 0; sl < NHW; ++sl) {
                    ebp[(row*NSL + wc*NHW + sl)*2 + 0] = ps[q][sl];
                    ebp[(row*NSL + wc*NHW + sl)*2 + 1] = pd[q][sl];
                }
            }
        }
        #pragma unroll
        for (int nt = 0; nt < 4; ++nt) {
            int col = cb + wc*64 + nt*16 + l15;
            #pragma unroll
            for (int q = 0; q < 4; ++q) {
                int r = rb + wr*64 + mt*16 + lg*4 + q;
                if (r < R) Hout[(size_t)r*M + col] = acc[mt][nt][q];
            }
        }
    }
    __syncthreads();
    for (int i = tid; i < 128*NSL; i += 256) {
        int row = i / NSL, sl = i - row*NSL;
        int r = rb + row;
        if (r < R) {
            es[(size_t)r*8 + hg0 + sl] = ebp[i*2 + 0];
            ed[(size_t)r*8 + hg0 + sl] = ebp[i*2 + 1];
        }
    }
}

// Layer-4 linear: X[R,128] @ W4[128,8] + e (H=1, C=8). 8 lanes per row.
__global__ __launch_bounds__(256) void k_lin4(
    const float* __restrict__ X, const float* __restrict__ W,
    const float* __restrict__ as_, const float* __restrict__ ad_,
    float* __restrict__ Hout, float* __restrict__ es, float* __restrict__ ed, int R) {
    int tid = threadIdx.x;
    int lane = tid & 63;
    int rl = lane >> 3, cc = lane & 7;
    int r = blockIdx.x*32 + (tid >> 6)*8 + rl;
    if (r >= R) return;
    const float* xp = X + (size_t)r*128;
    float acc = 0.f;
    #pragma unroll 8
    for (int k = 0; k < 128; ++k) acc += xp[k] * W[k*8 + cc];
    Hout[(size_t)r*8 + cc] = acc;
    float ps = acc * as_[cc], pd = acc * ad_[cc];
    #pragma unroll
    for (int off = 4; off >= 1; off >>= 1) {
        ps += __shfl_xor(ps, off, 64);
        pd += __shfl_xor(pd, off, 64);
    }
    if (cc == 0) { es[r] = ps; ed[r] = pd; }
}

// Mean-pool per (t, graph): out4[R,8] -> emb[T,B,8]
__global__ void k_pool(const float* __restrict__ x4, float* __restrict__ emb, int t0) {
    __shared__ float red[256];
    int tl = blockIdx.x >> 3, b = blockIdx.x & 7;
    int tid = threadIdx.x;
    int c = tid & 7, nl = tid >> 3;
    float s = 0.f;
    for (int k = 0; k < 34; ++k) {
        int n = nl + 32*k;
        if (n < NPG) s += x4[((size_t)tl*NN + b*NPG + n)*8 + c];
    }
    red[tid] = s;
    __syncthreads();
    for (int st = 16; st >= 1; st >>= 1) {
        if (nl < st) red[tid] += red[tid + st*8];
        __syncthreads();
    }
    if (nl == 0) emb[((t0 + tl)*8 + b)*8 + c] = red[c] * (1.f/1080.f);
}

// LSTM (one block per batch element) + final FC
__global__ __launch_bounds__(512) void k_lstm(
    const float* __restrict__ emb, const float* __restrict__ w_ih,
    const float* __restrict__ w_hh, const float* __restrict__ b_ih,
    const float* __restrict__ b_hh, const float* __restrict__ w_fc,
    const float* __restrict__ b_fc, float* __restrict__ out) {
    int b = blockIdx.x, u = threadIdx.x;
    __shared__ float h[128], cst[128], g[512];
    if (u < 128) { h[u] = 0.f; cst[u] = 0.f; }
    __syncthreads();
    float bsum = b_ih[u] + b_hh[u];
    for (int t = 0; t < T_TOT; ++t) {
        const float* e = emb + (t*8 + b)*8;
        float acc = bsum;
        #pragma unroll
        for (int k = 0; k < 8; ++k) acc += e[k]*w_ih[u*8 + k];
        for (int k = 0; k < 128; ++k) acc += h[k]*w_hh[u*128 + k];
        g[u] = acc;
        __syncthreads();
        if (u < 128) {
            float ig = 1.f/(1.f + __expf(-g[u]));
            float fg = 1.f/(1.f + __expf(-g[128+u]));
            float gg = tanhf(g[256+u]);
            float og = 1.f/(1.f + __expf(-g[384+u]));
            float cn = fg*cst[u] + ig*gg;
            cst[u] = cn;
            h[u] = og*tanhf(cn);
        }
        __syncthreads();
    }
    if (u < 2) {
        float acc = b_fc[u];
        for (int k = 0; k < 128; ++k) acc += h[k]*w_fc[u*128 + k];
        out[b*2 + u] = acc;
    }
}

extern "C" void kernel_launch(void* const* d_in, const int* in_sizes, int n_in,
                              void* d_out, int out_size, void* d_ws, size_t ws_size,
                              hipStream_t stream) {
    const float* x_seq = (const float*)d_in[0];
    const int*   edge  = (const int*)d_in[1];   // row0 = src
    const float* W1 = (const float*)d_in[3];
    const float* as1 = (const float*)d_in[4];
    const float* ad1 = (const float*)d_in[5];
    const float* b1  = (const float*)d_in[6];
    const float* W2 = (const float*)d_in[7];
    const float* as2 = (const float*)d_in[8];
    const float* ad2 = (const float*)d_in[9];
    const float* b2  = (const float*)d_in[10];
    const float* W3 = (const float*)d_in[11];
    const float* as3 = (const float*)d_in[12];
    const float* ad3 = (const float*)d_in[13];
    const float* b3  = (const float*)d_in[14];
    const float* W4 = (const float*)d_in[15];
    const float* as4 = (const float*)d_in[16];
    const float* ad4 = (const float*)d_in[17];
    const float* b4  = (const float*)d_in[18];
    const float* w_ih = (const float*)d_in[19];
    const float* w_hh = (const float*)d_in[20];
    const float* b_ih = (const float*)d_in[21];
    const float* b_hh = (const float*)d_in[22];
    const float* w_fc = (const float*)d_in[23];
    const float* b_fc = (const float*)d_in[24];

    char* w = (char*)d_ws;
    auto alloc = [&](size_t bytes) {
        char* p = w; w += (bytes + 255) & ~(size_t)255; return p;
    };
    float*   A1  = (float*)alloc(128);
    float*   emb = (float*)alloc((size_t)T_TOT*8*8*4);
    ushortT* W2T = (ushortT*)alloc((size_t)256*512*2);
    ushortT* W3T = (ushortT*)alloc((size_t)128*256*2);
    size_t used = (size_t)(w - (char*)d_ws);
    size_t perT = (size_t)NN*(2048 + 1024 + 4*32);   // QA + PB + ES/ED/P4/G5
    size_t rem = (ws_size > used + 4096) ? ws_size - used - 4096 : 0;
    int Tc = (int)(rem / perT);
    if (Tc > T_TOT) Tc = T_TOT;
    if (Tc < 1) Tc = 1;
    char*  QA = alloc((size_t)Tc*NN*2048);
    char*  PB = alloc((size_t)Tc*NN*1024);
    float* ES = (float*)alloc((size_t)Tc*NN*8*4);
    float* ED = (float*)alloc((size_t)Tc*NN*8*4);
    float* P4 = (float*)alloc((size_t)Tc*NN*8*4);
    float* G5 = (float*)alloc((size_t)Tc*NN*8*4);

    k_prep_l1<<<1, 64, 0, stream>>>(W1, as1, ad1, A1);
    k_prepW<<<(256*512 + 255)/256, 256, 0, stream>>>(W2, W2T, 512, 256);
    k_prepW<<<(128*256 + 255)/256, 256, 0, stream>>>(W3, W3T, 256, 128);

    for (int t0 = 0; t0 < T_TOT; t0 += Tc) {
        int tc = (Tc < T_TOT - t0) ? Tc : (T_TOT - t0);
        int R = tc*NN;
        int nrb = (R + 127)/128;
        const float* xoff = x_seq + (size_t)t0*NN*2;
        ushortT* Qhi = (ushortT*)QA;
        ushortT* Qlo = (ushortT*)(QA + (size_t)R*1024);
        float*   P   = (float*)PB;
        ushortT* G3hi= (ushortT*)QA;
        ushortT* G3lo= (ushortT*)(QA + (size_t)R*512);
        float*   H3  = (float*)PB;
        float*   G4  = (float*)(PB + (size_t)R*512);
        // Layer 1 (rank-2 shortcut, cooperative softmax) -> bf16 hi/lo
        k_e1<<<(R + 255)/256, 256, 0, stream>>>(xoff, A1, ES, ED, R);
        k_gat1<<<(R*8 + 15)/16, 256, 0, stream>>>(xoff, edge, ES, ED, W1, b1, Qhi, Qlo, R);
        // Layer 2: MFMA GEMM 512->256 (+es/ed), agg -> bf16 hi/lo
        k_gemm_mfma<32><<<dim3(nrb, 2), 256, 0, stream>>>(Qhi, Qlo, W2T, as2, ad2, P, ES, ED, R, 512, 256);
        k_gat<8,32,true><<<(R*8 + 31)/32, 256, 0, stream>>>(P, edge, ES, ED, b2, nullptr, G3hi, G3lo, R);
        // Layer 3: MFMA GEMM 256->128 (+es/ed), agg -> fp32
        k_gemm_mfma<16><<<dim3(nrb, 1), 256, 0, stream>>>(G3hi, G3lo, W3T, as3, ad3, H3, ES, ED, R, 256, 128);
        k_gat<8,16,false><<<(R*8 + 63)/64, 256, 0, stream>>>(H3, edge, ES, ED, b3, G4, nullptr, nullptr, R);
        // Layer 4: linear 128->8 (+e), agg
        k_lin4<<<R/32, 256, 0, stream>>>(G4, W4, as4, ad4, P4, ES, ED, R);
        k_gat<1,8,false><<<(R + 127)/128, 256, 0, stream>>>(P4, edge, ES, ED, b4, G5, nullptr, nullptr, R);
        // Pool
        k_pool<<<tc*8, 256, 0, stream>>>(G5, emb, t0);
    }
    k_lstm<<<8, 512, 0, stream>>>(emb, w_ih, w_hh, b_ih, b_hh, w_fc, b_fc, (float*)d_out);
}

// Round 5
// 493.891 us; speedup vs baseline: 3.1445x; 1.3194x over previous
//
#include <hip/hip_runtime.h>
#include <math.h>

#define T_TOT 10
#define NB    8
#define NPG   1080
#define NN    (NB*NPG)      // 8640 nodes
#define DEG   16

typedef unsigned short ushortT;
using short8 = __attribute__((ext_vector_type(8))) short;
using f32x4  = __attribute__((ext_vector_type(4))) float;

__device__ __forceinline__ float lrelu(float v) { return v > 0.f ? v : 0.2f*v; }
__device__ __forceinline__ float elu1(float v)  { return v > 0.f ? v : (__expf(v) - 1.f); }
__device__ __forceinline__ float bf2f(ushortT h){ return __uint_as_float(((unsigned)h) << 16); }
__device__ __forceinline__ ushortT rne(float v) {
    unsigned u = __float_as_uint(v);
    u += 0x7FFFu + ((u >> 16) & 1u);
    return (ushortT)(u >> 16);
}
// bijective XCD swizzle (8 XCDs): block b -> logical chunk so each XCD owns a
// contiguous range of work (L2 locality for the graph gathers). m204 formula.
__device__ __forceinline__ int xswz(int b, int nwg) {
    int q = nwg >> 3, r = nwg & 7;
    int x = b & 7, i = b >> 3;
    return x*q + min(x, r) + i;
}

// ---------------------------------------------------------------------------
// L1 precompute: A[sd][k][h] = dot(W1[k, h*64:(h+1)*64], att_{s,d}[h,:])
__global__ void k_prep_l1(const float* __restrict__ W1, const float* __restrict__ as1,
                          const float* __restrict__ ad1, float* __restrict__ A) {
    int tid = threadIdx.x;
    if (tid >= 32) return;
    int h = tid & 7, k = (tid >> 3) & 1, sd = tid >> 4;
    const float* att = sd ? ad1 : as1;
    float acc = 0.f;
    for (int c = 0; c < 64; ++c) acc += W1[k*512 + h*64 + c] * att[h*64 + c];
    A[sd*16 + k*8 + h] = acc;
}

// W [K,M] fp32 -> WT [M,K] bf16 (RNE)
__global__ void k_prepW(const float* __restrict__ W, ushortT* __restrict__ WT, int K, int M) {
    int i = blockIdx.x*256 + threadIdx.x;
    if (i >= K*M) return;
    int k = i / M, m = i - k*M;
    WT[(size_t)m*K + k] = rne(W[i]);
}

// e_s/e_d for layer 1 directly from x (rank-2)
__global__ void k_e1(const float* __restrict__ x, const float* __restrict__ A,
                     float* __restrict__ es, float* __restrict__ ed, int R) {
    int r = blockIdx.x*256 + threadIdx.x;
    if (r >= R) return;
    float x0 = x[2*r], x1 = x[2*r+1];
    #pragma unroll
    for (int h = 0; h < 8; ++h) {
        es[r*8+h] = x0*A[h]    + x1*A[8+h];
        ed[r*8+h] = x0*A[16+h] + x1*A[24+h];
    }
}

// Layer-1 fused attention+aggregate+linear+bias+ELU -> single bf16 plane.
__global__ __launch_bounds__(256) void k_gat1(
    const float* __restrict__ x, const int* __restrict__ esrc,
    const float* __restrict__ es, const float* __restrict__ ed,
    const float* __restrict__ W1, const float* __restrict__ b1,
    ushortT* __restrict__ q, int R) {
    int tid = threadIdx.x;
    int g = xswz(blockIdx.x, gridDim.x)*16 + (tid >> 4);   // group = r*8 + hh
    int l = tid & 15;
    if (g >= R*8) g = R*8 - 1;
    int r = g >> 3, hh = g & 7;
    int t = r / NN, n = r - t*NN;
    float edv = ed[r*8 + hh];
    int s0 = t*NN + esrc[n*DEG + l];
    float e0 = lrelu(es[s0*8 + hh] + edv);
    float e1 = (l == 0) ? lrelu(es[r*8 + hh] + edv) : -1e30f;
    float m = fmaxf(e0, e1);
    #pragma unroll
    for (int off = 8; off >= 1; off >>= 1) m = fmaxf(m, __shfl_xor(m, off, 16));
    float ex0 = __expf(e0 - m);
    float ex1 = (l == 0) ? __expf(e1 - m) : 0.f;
    float den = ex0 + ex1;
    float p0 = ex0*x[2*s0]   + ex1*x[2*r];
    float p1 = ex0*x[2*s0+1] + ex1*x[2*r+1];
    #pragma unroll
    for (int off = 8; off >= 1; off >>= 1) {
        den += __shfl_xor(den, off, 16);
        p0  += __shfl_xor(p0,  off, 16);
        p1  += __shfl_xor(p1,  off, 16);
    }
    float inv = 1.f/(den + 1e-16f);
    float xa0 = p0*inv, xa1 = p1*inv;
    int col = hh*64 + l*4;
    float4 w0 = *(const float4*)&W1[col];
    float4 w1 = *(const float4*)&W1[512 + col];
    float4 bb = *(const float4*)&b1[col];
    ushort4 h4;
    h4.x = rne(elu1(xa0*w0.x + xa1*w1.x + bb.x));
    h4.y = rne(elu1(xa0*w0.y + xa1*w1.y + bb.y));
    h4.z = rne(elu1(xa0*w0.z + xa1*w1.z + bb.z));
    h4.w = rne(elu1(xa0*w0.w + xa1*w1.w + bb.w));
    *(ushort4*)&q[(size_t)r*512 + col] = h4;
}

// Generic GAT attention+aggregate (+bias+ELU). BFIN: gather input bf16.
// BFOUT: store bf16 plane, else fp32. Cooperative softmax; XCD swizzle.
template<int H, int C, bool BFIN, bool BFOUT>
__global__ __launch_bounds__(256) void k_gat(
    const void* __restrict__ hb_, const int* __restrict__ esrc,
    const float* __restrict__ es, const float* __restrict__ ed,
    const float* __restrict__ bias, float* __restrict__ out,
    ushortT* __restrict__ ohi, int R) {
    constexpr int LANES = C/4;
    constexpr int GPB = 256/LANES;
    constexpr int EPL = (17 + LANES - 1)/LANES;
    __shared__ float wsm[GPB][17];
    __shared__ int   ssm[GPB][17];
    int tid = threadIdx.x;
    int grp = tid / LANES;
    int l = tid % LANES;
    int g = xswz(blockIdx.x, gridDim.x)*GPB + grp;   // group = r*H + hh
    if (g >= R*H) g = R*H - 1;
    int r = g / H, hh = g % H;
    int t = r / NN, n = r - t*NN;
    float edv = ed[(size_t)r*H + hh];
    float ev[EPL]; int sv[EPL];
    float m = -1e30f;
    #pragma unroll
    for (int s = 0; s < EPL; ++s) {
        int j = s*LANES + l;
        if (j < 17) {
            int src = (j == 16) ? r : (t*NN + esrc[n*DEG + j]);
            sv[s] = src;
            float e = lrelu(es[(size_t)src*H + hh] + edv);
            ev[s] = e; m = fmaxf(m, e);
        } else { ev[s] = -1e30f; sv[s] = r; }
    }
    #pragma unroll
    for (int off = LANES/2; off >= 1; off >>= 1) m = fmaxf(m, __shfl_xor(m, off, LANES));
    float den = 0.f;
    #pragma unroll
    for (int s = 0; s < EPL; ++s) {
        int j = s*LANES + l;
        float e2 = (j < 17) ? __expf(ev[s] - m) : 0.f;
        ev[s] = e2; den += e2;
    }
    #pragma unroll
    for (int off = LANES/2; off >= 1; off >>= 1) den += __shfl_xor(den, off, LANES);
    float inv = 1.f/(den + 1e-16f);
    #pragma unroll
    for (int s = 0; s < EPL; ++s) {
        int j = s*LANES + l;
        if (j < 17) { wsm[grp][j] = ev[s]*inv; ssm[grp][j] = sv[s]; }
    }
    __syncthreads();
    constexpr int HC = H*C;
    int base = hh*C + l*4;
    float ax = 0.f, ay = 0.f, az = 0.f, aw = 0.f;
    #pragma unroll
    for (int j = 0; j < 17; ++j) {
        float wj = wsm[grp][j];
        if constexpr (BFIN) {
            ushort4 hv = *(const ushort4*)&((const ushortT*)hb_)[(size_t)ssm[grp][j]*HC + base];
            ax += wj*bf2f(hv.x); ay += wj*bf2f(hv.y); az += wj*bf2f(hv.z); aw += wj*bf2f(hv.w);
        } else {
            float4 hv = *(const float4*)&((const float*)hb_)[(size_t)ssm[grp][j]*HC + base];
            ax += wj*hv.x; ay += wj*hv.y; az += wj*hv.z; aw += wj*hv.w;
        }
    }
    float4 bb = *(const float4*)&bias[base];
    float vx = elu1(ax + bb.x), vy = elu1(ay + bb.y);
    float vz = elu1(az + bb.z), vw = elu1(aw + bb.w);
    if constexpr (BFOUT) {
        ushort4 h4;
        h4.x = rne(vx); h4.y = rne(vy); h4.z = rne(vz); h4.w = rne(vw);
        *(ushort4*)&ohi[(size_t)r*HC + base] = h4;
    } else {
        *(float4*)&out[(size_t)r*HC + base] = make_float4(vx, vy, vz, vw);
    }
}

// MFMA GEMM: Hout[R,M](bf16) = X[R,K](bf16) @ WT[M,K](bf16)^T.
// 128x128 tile, 4 waves 2x2 (64x64 each, 4x4 frags of 16x16x32), BK=64.
// Fused es/ed epilogue (per-head dot with as_/ad_, C channels/head).
template<int C>
__global__ __launch_bounds__(256) void k_gemm_mfma(
    const ushortT* __restrict__ X, const ushortT* __restrict__ WT,
    const float* __restrict__ as_, const float* __restrict__ ad_,
    ushortT* __restrict__ Hout, float* __restrict__ es, float* __restrict__ ed,
    int R, int K, int M) {
    __shared__ __align__(16) char smem[32768];   // A 16K | B 16K
    int tid = threadIdx.x;
    int wid = tid >> 6, l = tid & 63;
    int l15 = l & 15, lg = l >> 4;
    int wr = wid >> 1, wc = wid & 1;
    int rb = blockIdx.x*128, cb = blockIdx.y*128;

    f32x4 acc[4][4] = {};
    int aoff[4], asw[4], boff[4], bsw[4];
    #pragma unroll
    for (int i = 0; i < 4; ++i) {
        int ar = wr*64 + i*16 + l15;
        aoff[i] = ar*128; asw[i] = (ar & 7) << 4;
        int bc = wc*64 + i*16 + l15;
        boff[i] = 16384 + bc*128; bsw[i] = (bc & 7) << 4;
    }
    int kb0 = lg*16;
    const size_t strideB = (size_t)K*2;
    int srow = tid >> 3, sc8 = tid & 7;      // staging: 4 row-strides of 32
    int ssw = ((srow & 7) << 4);
    const int nKT = K >> 6;

    for (int kt = 0; kt < nKT; ++kt) {
        int kbyte = kt*128;
        __syncthreads();
        #pragma unroll
        for (int i = 0; i < 4; ++i) {
            int row = srow + i*32;
            int dst = row*128 + ((sc8*16) ^ ssw);
            int rg = min(rb + row, R - 1);
            uint4 va = *(const uint4*)((const char*)X  + (size_t)rg*strideB + kbyte + sc8*16);
            uint4 vw = *(const uint4*)((const char*)WT + (size_t)(cb + row)*strideB + kbyte + sc8*16);
            *(uint4*)(smem + dst)         = va;
            *(uint4*)(smem + 16384 + dst) = vw;
        }
        __syncthreads();
        #pragma unroll
        for (int ks = 0; ks < 2; ++ks) {
            int kb = ks*64 + kb0;
            short8 ah[4], bv[4];
            #pragma unroll
            for (int i = 0; i < 4; ++i) {
                ah[i] = *(const short8*)(smem + aoff[i] + (kb ^ asw[i]));
                bv[i] = *(const short8*)(smem + boff[i] + (kb ^ bsw[i]));
            }
            #pragma unroll
            for (int mt = 0; mt < 4; ++mt)
                #pragma unroll
                for (int nt = 0; nt < 4; ++nt)
                    acc[mt][nt] = __builtin_amdgcn_mfma_f32_16x16x32_bf16(ah[mt], bv[nt], acc[mt][nt], 0, 0, 0);
        }
    }
    __syncthreads();
    // epilogue: es/ed per head + bf16 store
    constexpr int NSL = 128/C;               // head slots per block
    constexpr int NHW = 64/C;                // head slots per wave
    int hg0 = cb / C;
    float asv[4], adv[4];
    #pragma unroll
    for (int nt = 0; nt < 4; ++nt) {
        int col = wc*64 + nt*16 + l15;
        int h = col / C, c = col - h*C;
        asv[nt] = as_[(hg0 + h)*C + c];
        adv[nt] = ad_[(hg0 + h)*C + c];
    }
    float* ebp = (float*)smem;               // [128][NSL][2]
    #pragma unroll
    for (int mt = 0; mt < 4; ++mt) {
        float ps[4][NHW] = {}, pd[4][NHW] = {};
        #pragma unroll
        for (int nt = 0; nt < 4; ++nt) {
            int sl = (nt*16)/C;
            #pragma unroll
            for (int q = 0; q < 4; ++q) {
                ps[q][sl] += acc[mt][nt][q]*asv[nt];
                pd[q][sl] += acc[mt][nt][q]*adv[nt];
            }
        }
        #pragma unroll
        for (int off = 1; off < 16; off <<= 1)
            #pragma unroll
            for (int q = 0; q < 4; ++q)
                #pragma unroll
                for (int sl = 0; sl < NHW; ++sl) {
                    ps[q][sl] += __shfl_xor(ps[q][sl], off);
                    pd[q][sl] += __shfl_xor(pd[q][sl], off);
                }
        if (l15 == 0) {
            #pragma unroll
            for (int q = 0; q < 4; ++q) {
                int row = wr*64 + mt*16 + lg*4 + q;
                #pragma unroll
                for (int sl = 0; sl < NHW; ++sl) {
                    ebp[(row*NSL + wc*NHW + sl)*2 + 0] = ps[q][sl];
                    ebp[(row*NSL + wc*NHW + sl)*2 + 1] = pd[q][sl];
                }
            }
        }
        #pragma unroll
        for (int nt = 0; nt < 4; ++nt) {
            int col = cb + wc*64 + nt*16 + l15;
            #pragma unroll
            for (int q = 0; q < 4; ++q) {
                int r = rb + wr*64 + mt*16 + lg*4 + q;
                if (r < R) Hout[(size_t)r*M + col] = rne(acc[mt][nt][q]);
            }
        }
    }
    __syncthreads();
    for (int i = tid; i < 128*NSL; i += 256) {
        int row = i / NSL, sl = i - row*NSL;
        int r = rb + row;
        if (r < R) {
            es[(size_t)r*8 + hg0 + sl] = ebp[i*2 + 0];
            ed[(size_t)r*8 + hg0 + sl] = ebp[i*2 + 1];
        }
    }
}

// Layer-4 linear: X[R,128] @ W4[128,8] + e (H=1, C=8). 8 lanes per row.
__global__ __launch_bounds__(256) void k_lin4(
    const float* __restrict__ X, const float* __restrict__ W,
    const float* __restrict__ as_, const float* __restrict__ ad_,
    float* __restrict__ Hout, float* __restrict__ es, float* __restrict__ ed, int R) {
    int tid = threadIdx.x;
    int lane = tid & 63;
    int rl = lane >> 3, cc = lane & 7;
    int r = blockIdx.x*32 + (tid >> 6)*8 + rl;
    if (r >= R) return;
    const float* xp = X + (size_t)r*128;
    float acc = 0.f;
    #pragma unroll 8
    for (int k = 0; k < 128; ++k) acc += xp[k] * W[k*8 + cc];
    Hout[(size_t)r*8 + cc] = acc;
    float ps = acc * as_[cc], pd = acc * ad_[cc];
    #pragma unroll
    for (int off = 4; off >= 1; off >>= 1) {
        ps += __shfl_xor(ps, off, 64);
        pd += __shfl_xor(pd, off, 64);
    }
    if (cc == 0) { es[r] = ps; ed[r] = pd; }
}

// Mean-pool per (t, graph): out4[R,8] -> emb[T,B,8]
__global__ void k_pool(const float* __restrict__ x4, float* __restrict__ emb, int t0) {
    __shared__ float red[256];
    int tl = blockIdx.x >> 3, b = blockIdx.x & 7;
    int tid = threadIdx.x;
    int c = tid & 7, nl = tid >> 3;
    float s = 0.f;
    for (int k = 0; k < 34; ++k) {
        int n = nl + 32*k;
        if (n < NPG) s += x4[((size_t)tl*NN + b*NPG + n)*8 + c];
    }
    red[tid] = s;
    __syncthreads();
    for (int st = 16; st >= 1; st >>= 1) {
        if (nl < st) red[tid] += red[tid + st*8];
        __syncthreads();
    }
    if (nl == 0) emb[((t0 + tl)*8 + b)*8 + c] = red[c] * (1.f/1080.f);
}

// LSTM (one block per batch element) + final FC
__global__ __launch_bounds__(512) void k_lstm(
    const float* __restrict__ emb, const float* __restrict__ w_ih,
    const float* __restrict__ w_hh, const float* __restrict__ b_ih,
    const float* __restrict__ b_hh, const float* __restrict__ w_fc,
    const float* __restrict__ b_fc, float* __restrict__ out) {
    int b = blockIdx.x, u = threadIdx.x;
    __shared__ float h[128], cst[128], g[512];
    if (u < 128) { h[u] = 0.f; cst[u] = 0.f; }
    __syncthreads();
    float bsum = b_ih[u] + b_hh[u];
    for (int t = 0; t < T_TOT; ++t) {
        const float* e = emb + (t*8 + b)*8;
        float acc = bsum;
        #pragma unroll
        for (int k = 0; k < 8; ++k) acc += e[k]*w_ih[u*8 + k];
        for (int k = 0; k < 128; ++k) acc += h[k]*w_hh[u*128 + k];
        g[u] = acc;
        __syncthreads();
        if (u < 128) {
            float ig = 1.f/(1.f + __expf(-g[u]));
            float fg = 1.f/(1.f + __expf(-g[128+u]));
            float gg = tanhf(g[256+u]);
            float og = 1.f/(1.f + __expf(-g[384+u]));
            float cn = fg*cst[u] + ig*gg;
            cst[u] = cn;
            h[u] = og*tanhf(cn);
        }
        __syncthreads();
    }
    if (u < 2) {
        float acc = b_fc[u];
        for (int k = 0; k < 128; ++k) acc += h[k]*w_fc[u*128 + k];
        out[b*2 + u] = acc;
    }
}

extern "C" void kernel_launch(void* const* d_in, const int* in_sizes, int n_in,
                              void* d_out, int out_size, void* d_ws, size_t ws_size,
                              hipStream_t stream) {
    const float* x_seq = (const float*)d_in[0];
    const int*   edge  = (const int*)d_in[1];   // row0 = src
    const float* W1 = (const float*)d_in[3];
    const float* as1 = (const float*)d_in[4];
    const float* ad1 = (const float*)d_in[5];
    const float* b1  = (const float*)d_in[6];
    const float* W2 = (const float*)d_in[7];
    const float* as2 = (const float*)d_in[8];
    const float* ad2 = (const float*)d_in[9];
    const float* b2  = (const float*)d_in[10];
    const float* W3 = (const float*)d_in[11];
    const float* as3 = (const float*)d_in[12];
    const float* ad3 = (const float*)d_in[13];
    const float* b3  = (const float*)d_in[14];
    const float* W4 = (const float*)d_in[15];
    const float* as4 = (const float*)d_in[16];
    const float* ad4 = (const float*)d_in[17];
    const float* b4  = (const float*)d_in[18];
    const float* w_ih = (const float*)d_in[19];
    const float* w_hh = (const float*)d_in[20];
    const float* b_ih = (const float*)d_in[21];
    const float* b_hh = (const float*)d_in[22];
    const float* w_fc = (const float*)d_in[23];
    const float* b_fc = (const float*)d_in[24];

    char* w = (char*)d_ws;
    auto alloc = [&](size_t bytes) {
        char* p = w; w += (bytes + 255) & ~(size_t)255; return p;
    };
    float*   A1  = (float*)alloc(128);
    float*   emb = (float*)alloc((size_t)T_TOT*8*8*4);
    ushortT* W2T = (ushortT*)alloc((size_t)256*512*2);
    ushortT* W3T = (ushortT*)alloc((size_t)128*256*2);
    size_t used = (size_t)(w - (char*)d_ws);
    // per-row bytes: Q 1024 + P 512 + G3 512 + H3 256 + G4 512 + 4x32 fp32 vecs
    size_t perT = (size_t)NN*(1024 + 512 + 512 + 256 + 512 + 128);
    size_t rem = (ws_size > used + 4096) ? ws_size - used - 4096 : 0;
    int Tc = (int)(rem / perT);
    if (Tc > T_TOT) Tc = T_TOT;
    if (Tc < 1) Tc = 1;
    ushortT* Q  = (ushortT*)alloc((size_t)Tc*NN*1024);
    ushortT* P  = (ushortT*)alloc((size_t)Tc*NN*512);
    ushortT* G3 = (ushortT*)alloc((size_t)Tc*NN*512);
    ushortT* H3 = (ushortT*)alloc((size_t)Tc*NN*256);
    float*   G4 = (float*)alloc((size_t)Tc*NN*512);
    float*   ES = (float*)alloc((size_t)Tc*NN*32);
    float*   ED = (float*)alloc((size_t)Tc*NN*32);
    float*   P4 = (float*)alloc((size_t)Tc*NN*32);
    float*   G5 = (float*)alloc((size_t)Tc*NN*32);

    k_prep_l1<<<1, 64, 0, stream>>>(W1, as1, ad1, A1);
    k_prepW<<<(256*512 + 255)/256, 256, 0, stream>>>(W2, W2T, 512, 256);
    k_prepW<<<(128*256 + 255)/256, 256, 0, stream>>>(W3, W3T, 256, 128);

    for (int t0 = 0; t0 < T_TOT; t0 += Tc) {
        int tc = (Tc < T_TOT - t0) ? Tc : (T_TOT - t0);
        int R = tc*NN;
        int nrb = (R + 127)/128;
        const float* xoff = x_seq + (size_t)t0*NN*2;
        // Layer 1 (rank-2 shortcut, cooperative softmax) -> bf16
        k_e1<<<(R + 255)/256, 256, 0, stream>>>(xoff, A1, ES, ED, R);
        k_gat1<<<R/2, 256, 0, stream>>>(xoff, edge, ES, ED, W1, b1, Q, R);
        // Layer 2: MFMA GEMM 512->256 (+es/ed), agg -> bf16
        k_gemm_mfma<32><<<dim3(nrb, 2), 256, 0, stream>>>(Q, W2T, as2, ad2, P, ES, ED, R, 512, 256);
        k_gat<8,32,true,true><<<R/4, 256, 0, stream>>>(P, edge, ES, ED, b2, nullptr, G3, R);
        // Layer 3: MFMA GEMM 256->128 (+es/ed), agg -> fp32
        k_gemm_mfma<16><<<dim3(nrb, 1), 256, 0, stream>>>(G3, W3T, as3, ad3, H3, ES, ED, R, 256, 128);
        k_gat<8,16,true,false><<<R/8, 256, 0, stream>>>(H3, edge, ES, ED, b3, G4, nullptr, R);
        // Layer 4: linear 128->8 (+e), agg
        k_lin4<<<R/32, 256, 0, stream>>>(G4, W4, as4, ad4, P4, ES, ED, R);
        k_gat<1,8,false,false><<<(R + 127)/128, 256, 0, stream>>>(P4, edge, ES, ED, b4, G5, nullptr, R);
        // Pool
        k_pool<<<tc*8, 256, 0, stream>>>(G5, emb, t0);
    }
    k_lstm<<<8, 512, 0, stream>>>(emb, w_ih, w_hh, b_ih, b_hh, w_fc, b_fc, (float*)d_out);
}

// Round 6
// 437.778 us; speedup vs baseline: 3.5476x; 1.1282x over previous
//
#include <hip/hip_runtime.h>
#include <math.h>

#define T_TOT 10
#define NB    8
#define NPG   1080
#define NN    (NB*NPG)      // 8640 nodes
#define DEG   16

typedef unsigned short ushortT;
using short8 = __attribute__((ext_vector_type(8))) short;
using f32x4  = __attribute__((ext_vector_type(4))) float;

__device__ __forceinline__ float lrelu(float v) { return v > 0.f ? v : 0.2f*v; }
__device__ __forceinline__ float elu1(float v)  { return v > 0.f ? v : (__expf(v) - 1.f); }
__device__ __forceinline__ float bf2f(ushortT h){ return __uint_as_float(((unsigned)h) << 16); }
__device__ __forceinline__ ushortT rne(float v) {
    unsigned u = __float_as_uint(v);
    u += 0x7FFFu + ((u >> 16) & 1u);
    return (ushortT)(u >> 16);
}
// bijective XCD swizzle (8 XCDs): block b -> logical chunk so each XCD owns a
// contiguous range of work (L2 locality for the graph gathers). m204 formula.
__device__ __forceinline__ int xswz(int b, int nwg) {
    int q = nwg >> 3, r = nwg & 7;
    int x = b & 7, i = b >> 3;
    return x*q + min(x, r) + i;
}

// ---------------------------------------------------------------------------
// L1 precompute: A[sd][k][h] = dot(W1[k, h*64:(h+1)*64], att_{s,d}[h,:])
__global__ void k_prep_l1(const float* __restrict__ W1, const float* __restrict__ as1,
                          const float* __restrict__ ad1, float* __restrict__ A) {
    int tid = threadIdx.x;
    if (tid >= 32) return;
    int h = tid & 7, k = (tid >> 3) & 1, sd = tid >> 4;
    const float* att = sd ? ad1 : as1;
    float acc = 0.f;
    for (int c = 0; c < 64; ++c) acc += W1[k*512 + h*64 + c] * att[h*64 + c];
    A[sd*16 + k*8 + h] = acc;
}

// W [K,M] fp32 -> WT [M,K] bf16 (RNE)
__global__ void k_prepW(const float* __restrict__ W, ushortT* __restrict__ WT, int K, int M) {
    int i = blockIdx.x*256 + threadIdx.x;
    if (i >= K*M) return;
    int k = i / M, m = i - k*M;
    WT[(size_t)m*K + k] = rne(W[i]);
}

// e_s/e_d for layer 1 directly from x (rank-2)
__global__ void k_e1(const float* __restrict__ x, const float* __restrict__ A,
                     float* __restrict__ es, float* __restrict__ ed, int R) {
    int r = blockIdx.x*256 + threadIdx.x;
    if (r >= R) return;
    float x0 = x[2*r], x1 = x[2*r+1];
    #pragma unroll
    for (int h = 0; h < 8; ++h) {
        es[r*8+h] = x0*A[h]    + x1*A[8+h];
        ed[r*8+h] = x0*A[16+h] + x1*A[24+h];
    }
}

// Layer-1 fused attention+aggregate+linear+bias+ELU -> single bf16 plane.
__global__ __launch_bounds__(256) void k_gat1(
    const float* __restrict__ x, const int* __restrict__ esrc,
    const float* __restrict__ es, const float* __restrict__ ed,
    const float* __restrict__ W1, const float* __restrict__ b1,
    ushortT* __restrict__ q, int R) {
    int tid = threadIdx.x;
    int g = xswz(blockIdx.x, gridDim.x)*16 + (tid >> 4);   // group = r*8 + hh
    int l = tid & 15;
    if (g >= R*8) g = R*8 - 1;
    int r = g >> 3, hh = g & 7;
    int t = r / NN, n = r - t*NN;
    float edv = ed[r*8 + hh];
    int s0 = t*NN + esrc[n*DEG + l];
    float e0 = lrelu(es[s0*8 + hh] + edv);
    float e1 = (l == 0) ? lrelu(es[r*8 + hh] + edv) : -1e30f;
    float m = fmaxf(e0, e1);
    #pragma unroll
    for (int off = 8; off >= 1; off >>= 1) m = fmaxf(m, __shfl_xor(m, off, 16));
    float ex0 = __expf(e0 - m);
    float ex1 = (l == 0) ? __expf(e1 - m) : 0.f;
    float den = ex0 + ex1;
    float p0 = ex0*x[2*s0]   + ex1*x[2*r];
    float p1 = ex0*x[2*s0+1] + ex1*x[2*r+1];
    #pragma unroll
    for (int off = 8; off >= 1; off >>= 1) {
        den += __shfl_xor(den, off, 16);
        p0  += __shfl_xor(p0,  off, 16);
        p1  += __shfl_xor(p1,  off, 16);
    }
    float inv = 1.f/(den + 1e-16f);
    float xa0 = p0*inv, xa1 = p1*inv;
    int col = hh*64 + l*4;
    float4 w0 = *(const float4*)&W1[col];
    float4 w1 = *(const float4*)&W1[512 + col];
    float4 bb = *(const float4*)&b1[col];
    ushort4 h4;
    h4.x = rne(elu1(xa0*w0.x + xa1*w1.x + bb.x));
    h4.y = rne(elu1(xa0*w0.y + xa1*w1.y + bb.y));
    h4.z = rne(elu1(xa0*w0.z + xa1*w1.z + bb.z));
    h4.w = rne(elu1(xa0*w0.w + xa1*w1.w + bb.w));
    *(ushort4*)&q[(size_t)r*512 + col] = h4;
}

// Generic GAT attention+aggregate (+bias+ELU). BFIN: gather input bf16.
// BFOUT: store bf16 plane, else fp32. Cooperative softmax; XCD swizzle.
template<int H, int C, bool BFIN, bool BFOUT>
__global__ __launch_bounds__(256) void k_gat(
    const void* __restrict__ hb_, const int* __restrict__ esrc,
    const float* __restrict__ es, const float* __restrict__ ed,
    const float* __restrict__ bias, float* __restrict__ out,
    ushortT* __restrict__ ohi, int R) {
    constexpr int LANES = C/4;
    constexpr int GPB = 256/LANES;
    constexpr int EPL = (17 + LANES - 1)/LANES;
    __shared__ float wsm[GPB][17];
    __shared__ int   ssm[GPB][17];
    int tid = threadIdx.x;
    int grp = tid / LANES;
    int l = tid % LANES;
    int g = xswz(blockIdx.x, gridDim.x)*GPB + grp;   // group = r*H + hh
    if (g >= R*H) g = R*H - 1;
    int r = g / H, hh = g % H;
    int t = r / NN, n = r - t*NN;
    float edv = ed[(size_t)r*H + hh];
    float ev[EPL]; int sv[EPL];
    float m = -1e30f;
    #pragma unroll
    for (int s = 0; s < EPL; ++s) {
        int j = s*LANES + l;
        if (j < 17) {
            int src = (j == 16) ? r : (t*NN + esrc[n*DEG + j]);
            sv[s] = src;
            float e = lrelu(es[(size_t)src*H + hh] + edv);
            ev[s] = e; m = fmaxf(m, e);
        } else { ev[s] = -1e30f; sv[s] = r; }
    }
    #pragma unroll
    for (int off = LANES/2; off >= 1; off >>= 1) m = fmaxf(m, __shfl_xor(m, off, LANES));
    float den = 0.f;
    #pragma unroll
    for (int s = 0; s < EPL; ++s) {
        int j = s*LANES + l;
        float e2 = (j < 17) ? __expf(ev[s] - m) : 0.f;
        ev[s] = e2; den += e2;
    }
    #pragma unroll
    for (int off = LANES/2; off >= 1; off >>= 1) den += __shfl_xor(den, off, LANES);
    float inv = 1.f/(den + 1e-16f);
    #pragma unroll
    for (int s = 0; s < EPL; ++s) {
        int j = s*LANES + l;
        if (j < 17) { wsm[grp][j] = ev[s]*inv; ssm[grp][j] = sv[s]; }
    }
    __syncthreads();
    constexpr int HC = H*C;
    int base = hh*C + l*4;
    float ax = 0.f, ay = 0.f, az = 0.f, aw = 0.f;
    #pragma unroll
    for (int j = 0; j < 17; ++j) {
        float wj = wsm[grp][j];
        if constexpr (BFIN) {
            ushort4 hv = *(const ushort4*)&((const ushortT*)hb_)[(size_t)ssm[grp][j]*HC + base];
            ax += wj*bf2f(hv.x); ay += wj*bf2f(hv.y); az += wj*bf2f(hv.z); aw += wj*bf2f(hv.w);
        } else {
            float4 hv = *(const float4*)&((const float*)hb_)[(size_t)ssm[grp][j]*HC + base];
            ax += wj*hv.x; ay += wj*hv.y; az += wj*hv.z; aw += wj*hv.w;
        }
    }
    float4 bb = *(const float4*)&bias[base];
    float vx = elu1(ax + bb.x), vy = elu1(ay + bb.y);
    float vz = elu1(az + bb.z), vw = elu1(aw + bb.w);
    if constexpr (BFOUT) {
        ushort4 h4;
        h4.x = rne(vx); h4.y = rne(vy); h4.z = rne(vz); h4.w = rne(vw);
        *(ushort4*)&ohi[(size_t)r*HC + base] = h4;
    } else {
        *(float4*)&out[(size_t)r*HC + base] = make_float4(vx, vy, vz, vw);
    }
}

// MFMA GEMM: Hout[R,M](bf16) = X[R,K](bf16) @ WT[M,K](bf16)^T.
// 128x128 tile, 4 waves 2x2 (64x64 each, 4x4 frags of 16x16x32), BK=64.
// Fused es/ed epilogue (per-head dot with as_/ad_, C channels/head).
template<int C>
__global__ __launch_bounds__(256) void k_gemm_mfma(
    const ushortT* __restrict__ X, const ushortT* __restrict__ WT,
    const float* __restrict__ as_, const float* __restrict__ ad_,
    ushortT* __restrict__ Hout, float* __restrict__ es, float* __restrict__ ed,
    int R, int K, int M) {
    __shared__ __align__(16) char smem[32768];   // A 16K | B 16K
    int tid = threadIdx.x;
    int wid = tid >> 6, l = tid & 63;
    int l15 = l & 15, lg = l >> 4;
    int wr = wid >> 1, wc = wid & 1;
    int rb = blockIdx.x*128, cb = blockIdx.y*128;

    f32x4 acc[4][4] = {};
    int aoff[4], asw[4], boff[4], bsw[4];
    #pragma unroll
    for (int i = 0; i < 4; ++i) {
        int ar = wr*64 + i*16 + l15;
        aoff[i] = ar*128; asw[i] = (ar & 7) << 4;
        int bc = wc*64 + i*16 + l15;
        boff[i] = 16384 + bc*128; bsw[i] = (bc & 7) << 4;
    }
    int kb0 = lg*16;
    const size_t strideB = (size_t)K*2;
    int srow = tid >> 3, sc8 = tid & 7;      // staging: 4 row-strides of 32
    int ssw = ((srow & 7) << 4);
    const int nKT = K >> 6;

    for (int kt = 0; kt < nKT; ++kt) {
        int kbyte = kt*128;
        __syncthreads();
        #pragma unroll
        for (int i = 0; i < 4; ++i) {
            int row = srow + i*32;
            int dst = row*128 + ((sc8*16) ^ ssw);
            int rg = min(rb + row, R - 1);
            uint4 va = *(const uint4*)((const char*)X  + (size_t)rg*strideB + kbyte + sc8*16);
            uint4 vw = *(const uint4*)((const char*)WT + (size_t)(cb + row)*strideB + kbyte + sc8*16);
            *(uint4*)(smem + dst)         = va;
            *(uint4*)(smem + 16384 + dst) = vw;
        }
        __syncthreads();
        #pragma unroll
        for (int ks = 0; ks < 2; ++ks) {
            int kb = ks*64 + kb0;
            short8 ah[4], bv[4];
            #pragma unroll
            for (int i = 0; i < 4; ++i) {
                ah[i] = *(const short8*)(smem + aoff[i] + (kb ^ asw[i]));
                bv[i] = *(const short8*)(smem + boff[i] + (kb ^ bsw[i]));
            }
            #pragma unroll
            for (int mt = 0; mt < 4; ++mt)
                #pragma unroll
                for (int nt = 0; nt < 4; ++nt)
                    acc[mt][nt] = __builtin_amdgcn_mfma_f32_16x16x32_bf16(ah[mt], bv[nt], acc[mt][nt], 0, 0, 0);
        }
    }
    __syncthreads();
    // epilogue: es/ed per head + bf16 store
    constexpr int NSL = 128/C;               // head slots per block
    constexpr int NHW = 64/C;                // head slots per wave
    int hg0 = cb / C;
    float asv[4], adv[4];
    #pragma unroll
    for (int nt = 0; nt < 4; ++nt) {
        int col = wc*64 + nt*16 + l15;
        int h = col / C, c = col - h*C;
        asv[nt] = as_[(hg0 + h)*C + c];
        adv[nt] = ad_[(hg0 + h)*C + c];
    }
    float* ebp = (float*)smem;               // [128][NSL][2]
    #pragma unroll
    for (int mt = 0; mt < 4; ++mt) {
        float ps[4][NHW] = {}, pd[4][NHW] = {};
        #pragma unroll
        for (int nt = 0; nt < 4; ++nt) {
            int sl = (nt*16)/C;
            #pragma unroll
            for (int q = 0; q < 4; ++q) {
                ps[q][sl] += acc[mt][nt][q]*asv[nt];
                pd[q][sl] += acc[mt][nt][q]*adv[nt];
            }
        }
        #pragma unroll
        for (int off = 1; off < 16; off <<= 1)
            #pragma unroll
            for (int q = 0; q < 4; ++q)
                #pragma unroll
                for (int sl = 0; sl < NHW; ++sl) {
                    ps[q][sl] += __shfl_xor(ps[q][sl], off);
                    pd[q][sl] += __shfl_xor(pd[q][sl], off);
                }
        if (l15 == 0) {
            #pragma unroll
            for (int q = 0; q < 4; ++q) {
                int row = wr*64 + mt*16 + lg*4 + q;
                #pragma unroll
                for (int sl = 0; sl < NHW; ++sl) {
                    ebp[(row*NSL + wc*NHW + sl)*2 + 0] = ps[q][sl];
                    ebp[(row*NSL + wc*NHW + sl)*2 + 1] = pd[q][sl];
                }
            }
        }
        #pragma unroll
        for (int nt = 0; nt < 4; ++nt) {
            int col = cb + wc*64 + nt*16 + l15;
            #pragma unroll
            for (int q = 0; q < 4; ++q) {
                int r = rb + wr*64 + mt*16 + lg*4 + q;
                if (r < R) Hout[(size_t)r*M + col] = rne(acc[mt][nt][q]);
            }
        }
    }
    __syncthreads();
    for (int i = tid; i < 128*NSL; i += 256) {
        int row = i / NSL, sl = i - row*NSL;
        int r = rb + row;
        if (r < R) {
            es[(size_t)r*8 + hg0 + sl] = ebp[i*2 + 0];
            ed[(size_t)r*8 + hg0 + sl] = ebp[i*2 + 1];
        }
    }
}

// Layer-4 linear: X[R,128] @ W4[128,8] + e (H=1, C=8). 8 lanes per row.
__global__ __launch_bounds__(256) void k_lin4(
    const float* __restrict__ X, const float* __restrict__ W,
    const float* __restrict__ as_, const float* __restrict__ ad_,
    float* __restrict__ Hout, float* __restrict__ es, float* __restrict__ ed, int R) {
    int tid = threadIdx.x;
    int lane = tid & 63;
    int rl = lane >> 3, cc = lane & 7;
    int r = blockIdx.x*32 + (tid >> 6)*8 + rl;
    if (r >= R) return;
    const float* xp = X + (size_t)r*128;
    float acc = 0.f;
    #pragma unroll 8
    for (int k = 0; k < 128; ++k) acc += xp[k] * W[k*8 + cc];
    Hout[(size_t)r*8 + cc] = acc;
    float ps = acc * as_[cc], pd = acc * ad_[cc];
    #pragma unroll
    for (int off = 4; off >= 1; off >>= 1) {
        ps += __shfl_xor(ps, off, 64);
        pd += __shfl_xor(pd, off, 64);
    }
    if (cc == 0) { es[r] = ps; ed[r] = pd; }
}

// Mean-pool per (t, graph): out4[R,8] -> emb[T,B,8]
__global__ void k_pool(const float* __restrict__ x4, float* __restrict__ emb, int t0) {
    __shared__ float red[256];
    int tl = blockIdx.x >> 3, b = blockIdx.x & 7;
    int tid = threadIdx.x;
    int c = tid & 7, nl = tid >> 3;
    float s = 0.f;
    for (int k = 0; k < 34; ++k) {
        int n = nl + 32*k;
        if (n < NPG) s += x4[((size_t)tl*NN + b*NPG + n)*8 + c];
    }
    red[tid] = s;
    __syncthreads();
    for (int st = 16; st >= 1; st >>= 1) {
        if (nl < st) red[tid] += red[tid + st*8];
        __syncthreads();
    }
    if (nl == 0) emb[((t0 + tl)*8 + b)*8 + c] = red[c] * (1.f/1080.f);
}

// LSTM (one block per batch element) + final FC.
// w_hh row register-resident per thread (128 VGPRs, static indexing via full
// unroll); h broadcast from LDS; 4 accumulators break the FMA chain.
__global__ __launch_bounds__(512) void k_lstm(
    const float* __restrict__ emb, const float* __restrict__ w_ih,
    const float* __restrict__ w_hh, const float* __restrict__ b_ih,
    const float* __restrict__ b_hh, const float* __restrict__ w_fc,
    const float* __restrict__ b_fc, float* __restrict__ out) {
    int b = blockIdx.x, u = threadIdx.x;
    __shared__ float h[128], cst[128], g[512], eall[T_TOT*8];
    if (u < 128) { h[u] = 0.f; cst[u] = 0.f; }
    if (u < T_TOT*8) eall[u] = emb[((u >> 3)*8 + b)*8 + (u & 7)];
    // stage weights into registers (one row per thread)
    float wreg[128];
    {
        const float* wp = w_hh + (size_t)u*128;
        #pragma unroll
        for (int k4 = 0; k4 < 32; ++k4) {
            float4 v = *(const float4*)&wp[k4*4];
            wreg[4*k4+0] = v.x; wreg[4*k4+1] = v.y;
            wreg[4*k4+2] = v.z; wreg[4*k4+3] = v.w;
        }
    }
    float wih[8];
    #pragma unroll
    for (int k = 0; k < 8; ++k) wih[k] = w_ih[(size_t)u*8 + k];
    float bsum = b_ih[u] + b_hh[u];
    __syncthreads();
    for (int t = 0; t < T_TOT; ++t) {
        float a0 = bsum, a1 = 0.f, a2 = 0.f, a3 = 0.f;
        #pragma unroll
        for (int k = 0; k < 8; ++k) a0 += eall[t*8 + k]*wih[k];
        #pragma unroll
        for (int k = 0; k < 32; ++k) {
            a0 += h[4*k+0]*wreg[4*k+0];
            a1 += h[4*k+1]*wreg[4*k+1];
            a2 += h[4*k+2]*wreg[4*k+2];
            a3 += h[4*k+3]*wreg[4*k+3];
        }
        g[u] = (a0 + a1) + (a2 + a3);
        __syncthreads();
        if (u < 128) {
            float ig = 1.f/(1.f + __expf(-g[u]));
            float fg = 1.f/(1.f + __expf(-g[128+u]));
            float gg = tanhf(g[256+u]);
            float og = 1.f/(1.f + __expf(-g[384+u]));
            float cn = fg*cst[u] + ig*gg;
            cst[u] = cn;
            h[u] = og*tanhf(cn);
        }
        __syncthreads();
    }
    if (u < 64) {
        float p0 = h[u]*w_fc[u]       + h[u+64]*w_fc[64+u];
        float p1 = h[u]*w_fc[128+u]   + h[u+64]*w_fc[192+u];
        #pragma unroll
        for (int off = 32; off >= 1; off >>= 1) {
            p0 += __shfl_xor(p0, off, 64);
            p1 += __shfl_xor(p1, off, 64);
        }
        if (u == 0) {
            out[b*2 + 0] = p0 + b_fc[0];
            out[b*2 + 1] = p1 + b_fc[1];
        }
    }
}

extern "C" void kernel_launch(void* const* d_in, const int* in_sizes, int n_in,
                              void* d_out, int out_size, void* d_ws, size_t ws_size,
                              hipStream_t stream) {
    const float* x_seq = (const float*)d_in[0];
    const int*   edge  = (const int*)d_in[1];   // row0 = src
    const float* W1 = (const float*)d_in[3];
    const float* as1 = (const float*)d_in[4];
    const float* ad1 = (const float*)d_in[5];
    const float* b1  = (const float*)d_in[6];
    const float* W2 = (const float*)d_in[7];
    const float* as2 = (const float*)d_in[8];
    const float* ad2 = (const float*)d_in[9];
    const float* b2  = (const float*)d_in[10];
    const float* W3 = (const float*)d_in[11];
    const float* as3 = (const float*)d_in[12];
    const float* ad3 = (const float*)d_in[13];
    const float* b3  = (const float*)d_in[14];
    const float* W4 = (const float*)d_in[15];
    const float* as4 = (const float*)d_in[16];
    const float* ad4 = (const float*)d_in[17];
    const float* b4  = (const float*)d_in[18];
    const float* w_ih = (const float*)d_in[19];
    const float* w_hh = (const float*)d_in[20];
    const float* b_ih = (const float*)d_in[21];
    const float* b_hh = (const float*)d_in[22];
    const float* w_fc = (const float*)d_in[23];
    const float* b_fc = (const float*)d_in[24];

    char* w = (char*)d_ws;
    auto alloc = [&](size_t bytes) {
        char* p = w; w += (bytes + 255) & ~(size_t)255; return p;
    };
    float*   A1  = (float*)alloc(128);
    float*   emb = (float*)alloc((size_t)T_TOT*8*8*4);
    ushortT* W2T = (ushortT*)alloc((size_t)256*512*2);
    ushortT* W3T = (ushortT*)alloc((size_t)128*256*2);
    size_t used = (size_t)(w - (char*)d_ws);
    // per-row bytes: Q 1024 + P 512 + G3 512 + H3 256 + G4 512 + 4x32 fp32 vecs
    size_t perT = (size_t)NN*(1024 + 512 + 512 + 256 + 512 + 128);
    size_t rem = (ws_size > used + 4096) ? ws_size - used - 4096 : 0;
    int Tc = (int)(rem / perT);
    if (Tc > T_TOT) Tc = T_TOT;
    if (Tc < 1) Tc = 1;
    ushortT* Q  = (ushortT*)alloc((size_t)Tc*NN*1024);
    ushortT* P  = (ushortT*)alloc((size_t)Tc*NN*512);
    ushortT* G3 = (ushortT*)alloc((size_t)Tc*NN*512);
    ushortT* H3 = (ushortT*)alloc((size_t)Tc*NN*256);
    float*   G4 = (float*)alloc((size_t)Tc*NN*512);
    float*   ES = (float*)alloc((size_t)Tc*NN*32);
    float*   ED = (float*)alloc((size_t)Tc*NN*32);
    float*   P4 = (float*)alloc((size_t)Tc*NN*32);
    float*   G5 = (float*)alloc((size_t)Tc*NN*32);

    k_prep_l1<<<1, 64, 0, stream>>>(W1, as1, ad1, A1);
    k_prepW<<<(256*512 + 255)/256, 256, 0, stream>>>(W2, W2T, 512, 256);
    k_prepW<<<(128*256 + 255)/256, 256, 0, stream>>>(W3, W3T, 256, 128);

    for (int t0 = 0; t0 < T_TOT; t0 += Tc) {
        int tc = (Tc < T_TOT - t0) ? Tc : (T_TOT - t0);
        int R = tc*NN;
        int nrb = (R + 127)/128;
        const float* xoff = x_seq + (size_t)t0*NN*2;
        // Layer 1 (rank-2 shortcut, cooperative softmax) -> bf16
        k_e1<<<(R + 255)/256, 256, 0, stream>>>(xoff, A1, ES, ED, R);
        k_gat1<<<R/2, 256, 0, stream>>>(xoff, edge, ES, ED, W1, b1, Q, R);
        // Layer 2: MFMA GEMM 512->256 (+es/ed), agg -> bf16
        k_gemm_mfma<32><<<dim3(nrb, 2), 256, 0, stream>>>(Q, W2T, as2, ad2, P, ES, ED, R, 512, 256);
        k_gat<8,32,true,true><<<R/4, 256, 0, stream>>>(P, edge, ES, ED, b2, nullptr, G3, R);
        // Layer 3: MFMA GEMM 256->128 (+es/ed), agg -> fp32
        k_gemm_mfma<16><<<dim3(nrb, 1), 256, 0, stream>>>(G3, W3T, as3, ad3, H3, ES, ED, R, 256, 128);
        k_gat<8,16,true,false><<<R/8, 256, 0, stream>>>(H3, edge, ES, ED, b3, G4, nullptr, R);
        // Layer 4: linear 128->8 (+e), agg
        k_lin4<<<R/32, 256, 0, stream>>>(G4, W4, as4, ad4, P4, ES, ED, R);
        k_gat<1,8,false,false><<<(R + 127)/128, 256, 0, stream>>>(P4, edge, ES, ED, b4, G5, nullptr, R);
        // Pool
        k_pool<<<tc*8, 256, 0, stream>>>(G5, emb, t0);
    }
    k_lstm<<<8, 512, 0, stream>>>(emb, w_ih, w_hh, b_ih, b_hh, w_fc, b_fc, (float*)d_out);
}

// Round 7
// 400.601 us; speedup vs baseline: 3.8768x; 1.0928x over previous
//
#include <hip/hip_runtime.h>
#include <math.h>

#define T_TOT 10
#define NB    8
#define NPG   1080
#define NN    (NB*NPG)      // 8640 nodes
#define DEG   16

typedef unsigned short ushortT;
using short8 = __attribute__((ext_vector_type(8))) short;
using f32x4  = __attribute__((ext_vector_type(4))) float;

__device__ __forceinline__ float lrelu(float v) { return v > 0.f ? v : 0.2f*v; }
__device__ __forceinline__ float elu1(float v)  { return v > 0.f ? v : (__expf(v) - 1.f); }
__device__ __forceinline__ float bf2f(ushortT h){ return __uint_as_float(((unsigned)h) << 16); }
__device__ __forceinline__ float bfl(unsigned u){ return __uint_as_float(u << 16); }
__device__ __forceinline__ float bfh(unsigned u){ return __uint_as_float(u & 0xFFFF0000u); }
__device__ __forceinline__ ushortT rne(float v) {
    unsigned u = __float_as_uint(v);
    u += 0x7FFFu + ((u >> 16) & 1u);
    return (ushortT)(u >> 16);
}
__device__ __forceinline__ unsigned pk2(float a, float b) {
    return (unsigned)rne(a) | ((unsigned)rne(b) << 16);
}
// bijective XCD swizzle (8 XCDs): contiguous work range per XCD (L2 locality).
__device__ __forceinline__ int xswz(int b, int nwg) {
    int q = nwg >> 3, r = nwg & 7;
    int x = b & 7, i = b >> 3;
    return x*q + min(x, r) + i;
}

// ---------------------------------------------------------------------------
// L1 precompute: A[sd][k][h] = dot(W1[k, h*64:(h+1)*64], att_{s,d}[h,:])
__global__ void k_prep_l1(const float* __restrict__ W1, const float* __restrict__ as1,
                          const float* __restrict__ ad1, float* __restrict__ A) {
    int tid = threadIdx.x;
    if (tid >= 32) return;
    int h = tid & 7, k = (tid >> 3) & 1, sd = tid >> 4;
    const float* att = sd ? ad1 : as1;
    float acc = 0.f;
    for (int c = 0; c < 64; ++c) acc += W1[k*512 + h*64 + c] * att[h*64 + c];
    A[sd*16 + k*8 + h] = acc;
}

// W [K,M] fp32 -> WT [M,K] bf16 (RNE)
__global__ void k_prepW(const float* __restrict__ W, ushortT* __restrict__ WT, int K, int M) {
    int i = blockIdx.x*256 + threadIdx.x;
    if (i >= K*M) return;
    int k = i / M, m = i - k*M;
    WT[(size_t)m*K + k] = rne(W[i]);
}

// Layer-1: fused e-compute (rank-2) + attention + aggregate + linear + ELU -> bf16.
// 8 lanes per (r,head); register softmax, shfl reductions, no LDS/barrier.
__global__ __launch_bounds__(256) void k_gat1(
    const float* __restrict__ x, const int* __restrict__ esrc,
    const float* __restrict__ A, const float* __restrict__ W1,
    const float* __restrict__ b1, ushortT* __restrict__ q, int R) {
    int tid = threadIdx.x;
    int g = xswz(blockIdx.x, gridDim.x)*32 + (tid >> 3);   // group = r*8 + hh
    int l = tid & 7;
    if (g >= R*8) g = R*8 - 1;
    int r = g >> 3, hh = g & 7;
    int t = r / NN, n = r - t*NN;
    float2 xr = *(const float2*)&x[2*r];
    float As0 = A[hh], As1 = A[8+hh];
    float edv = xr.x*A[16+hh] + xr.y*A[24+hh];
    float ev[3], xs0[3], xs1[3];
    float m = -1e30f;
    #pragma unroll
    for (int s = 0; s < 3; ++s) {
        int j = s*8 + l;
        if (j < 17) {
            int src = (j == 16) ? r : (t*NN + esrc[n*DEG + j]);
            float2 xs = *(const float2*)&x[2*src];
            xs0[s] = xs.x; xs1[s] = xs.y;
            float e = lrelu(xs.x*As0 + xs.y*As1 + edv);
            ev[s] = e; m = fmaxf(m, e);
        } else { ev[s] = -1e30f; xs0[s] = 0.f; xs1[s] = 0.f; }
    }
    #pragma unroll
    for (int off = 4; off >= 1; off >>= 1) m = fmaxf(m, __shfl_xor(m, off, 8));
    float den = 0.f, p0 = 0.f, p1 = 0.f;
    #pragma unroll
    for (int s = 0; s < 3; ++s) {
        float e2 = __expf(ev[s] - m);
        den += e2; p0 += e2*xs0[s]; p1 += e2*xs1[s];
    }
    #pragma unroll
    for (int off = 4; off >= 1; off >>= 1) {
        den += __shfl_xor(den, off, 8);
        p0  += __shfl_xor(p0,  off, 8);
        p1  += __shfl_xor(p1,  off, 8);
    }
    float inv = 1.f/(den + 1e-16f);
    float xa0 = p0*inv, xa1 = p1*inv;
    int col = hh*64 + l*8;
    float4 w0a = *(const float4*)&W1[col],       w0b = *(const float4*)&W1[col+4];
    float4 w1a = *(const float4*)&W1[512+col],   w1b = *(const float4*)&W1[512+col+4];
    float4 bba = *(const float4*)&b1[col],       bbb = *(const float4*)&b1[col+4];
    float v0 = elu1(xa0*w0a.x + xa1*w1a.x + bba.x);
    float v1 = elu1(xa0*w0a.y + xa1*w1a.y + bba.y);
    float v2 = elu1(xa0*w0a.z + xa1*w1a.z + bba.z);
    float v3 = elu1(xa0*w0a.w + xa1*w1a.w + bba.w);
    float v4 = elu1(xa0*w0b.x + xa1*w1b.x + bbb.x);
    float v5 = elu1(xa0*w0b.y + xa1*w1b.y + bbb.y);
    float v6 = elu1(xa0*w0b.z + xa1*w1b.z + bbb.z);
    float v7 = elu1(xa0*w0b.w + xa1*w1b.w + bbb.w);
    uint4 o;
    o.x = pk2(v0,v1); o.y = pk2(v2,v3); o.z = pk2(v4,v5); o.w = pk2(v6,v7);
    *(uint4*)&q[(size_t)r*512 + col] = o;
}

// Generic GAT attention+aggregate (+bias+ELU). Register softmax + shfl
// broadcast; no LDS, no barrier. BFIN: bf16 input (8 ch/lane, 16B gathers);
// else fp32 (4 ch/lane). BFOUT: bf16 output.
template<int H, int C, int LANES, bool BFIN, bool BFOUT>
__global__ __launch_bounds__(256) void k_gat(
    const void* __restrict__ hb_, const int* __restrict__ esrc,
    const float* __restrict__ es, const float* __restrict__ ed,
    const float* __restrict__ bias, float* __restrict__ out,
    ushortT* __restrict__ ohi, int R) {
    constexpr int CPL = C/LANES;                 // 8 (bf16) or 4 (fp32)
    constexpr int GPB = 256/LANES;
    constexpr int EPL = (17 + LANES - 1)/LANES;
    constexpr int HC = H*C;
    int tid = threadIdx.x;
    int l = tid & (LANES-1);
    int g = xswz(blockIdx.x, gridDim.x)*GPB + tid/LANES;   // group = r*H + hh
    if (g >= R*H) g = R*H - 1;
    int r = g / H, hh = g % H;
    int t = r / NN, n = r - t*NN;
    float edv = ed[(size_t)r*H + hh];
    float ev[EPL]; int sv[EPL];
    float m = -1e30f;
    #pragma unroll
    for (int s = 0; s < EPL; ++s) {
        int j = s*LANES + l;
        if (j < 17) {
            int src = (j == 16) ? r : (t*NN + esrc[n*DEG + j]);
            sv[s] = src;
            float e = lrelu(es[(size_t)src*H + hh] + edv);
            ev[s] = e; m = fmaxf(m, e);
        } else { ev[s] = -1e30f; sv[s] = r; }
    }
    #pragma unroll
    for (int off = LANES/2; off >= 1; off >>= 1) m = fmaxf(m, __shfl_xor(m, off, LANES));
    float den = 0.f;
    float wv[EPL];
    #pragma unroll
    for (int s = 0; s < EPL; ++s) {
        float e2 = __expf(ev[s] - m);
        wv[s] = e2; den += e2;
    }
    #pragma unroll
    for (int off = LANES/2; off >= 1; off >>= 1) den += __shfl_xor(den, off, LANES);
    float inv = 1.f/(den + 1e-16f);
    #pragma unroll
    for (int s = 0; s < EPL; ++s) wv[s] *= inv;

    int lb = (tid & 63) & ~(LANES-1);            // group's base lane (abs)
    float acc[CPL] = {};
    #pragma unroll
    for (int j = 0; j < 17; ++j) {
        float wj = __shfl(wv[j/LANES], lb + (j & (LANES-1)), 64);
        int   sj = __shfl(sv[j/LANES], lb + (j & (LANES-1)), 64);
        if constexpr (BFIN) {
            const ushortT* hp = (const ushortT*)hb_ + (size_t)sj*HC + hh*C + l*CPL;
            uint4 hv = *(const uint4*)hp;
            acc[0] += wj*bfl(hv.x); acc[1] += wj*bfh(hv.x);
            acc[2] += wj*bfl(hv.y); acc[3] += wj*bfh(hv.y);
            acc[4] += wj*bfl(hv.z); acc[5] += wj*bfh(hv.z);
            acc[6] += wj*bfl(hv.w); acc[7] += wj*bfh(hv.w);
        } else {
            const float* hp = (const float*)hb_ + (size_t)sj*HC + hh*C + l*CPL;
            float4 hv = *(const float4*)hp;
            acc[0] += wj*hv.x; acc[1] += wj*hv.y;
            acc[2] += wj*hv.z; acc[3] += wj*hv.w;
        }
    }
    int base = hh*C + l*CPL;
    #pragma unroll
    for (int c = 0; c < CPL; ++c) acc[c] = elu1(acc[c] + bias[base + c]);
    if constexpr (BFOUT) {
        uint4 o;
        o.x = pk2(acc[0],acc[1]); o.y = pk2(acc[2],acc[3]);
        o.z = pk2(acc[4],acc[5]); o.w = pk2(acc[6],acc[7]);
        *(uint4*)&ohi[(size_t)r*HC + base] = o;
    } else {
        *(float4*)&out[(size_t)r*HC + base] = make_float4(acc[0],acc[1],acc[2],acc[3]);
    }
}

// MFMA GEMM: Hout[R,M](bf16) = X[R,K](bf16) @ WT[M,K](bf16)^T.
// 128x128 tile, 4 waves 2x2, BK=64, fused es/ed epilogue.
template<int C>
__global__ __launch_bounds__(256) void k_gemm_mfma(
    const ushortT* __restrict__ X, const ushortT* __restrict__ WT,
    const float* __restrict__ as_, const float* __restrict__ ad_,
    ushortT* __restrict__ Hout, float* __restrict__ es, float* __restrict__ ed,
    int R, int K, int M) {
    __shared__ __align__(16) char smem[32768];   // A 16K | B 16K
    int tid = threadIdx.x;
    int wid = tid >> 6, l = tid & 63;
    int l15 = l & 15, lg = l >> 4;
    int wr = wid >> 1, wc = wid & 1;
    int rb = blockIdx.x*128, cb = blockIdx.y*128;

    f32x4 acc[4][4] = {};
    int aoff[4], asw[4], boff[4], bsw[4];
    #pragma unroll
    for (int i = 0; i < 4; ++i) {
        int ar = wr*64 + i*16 + l15;
        aoff[i] = ar*128; asw[i] = (ar & 7) << 4;
        int bc = wc*64 + i*16 + l15;
        boff[i] = 16384 + bc*128; bsw[i] = (bc & 7) << 4;
    }
    int kb0 = lg*16;
    const size_t strideB = (size_t)K*2;
    int srow = tid >> 3, sc8 = tid & 7;
    int ssw = ((srow & 7) << 4);
    const int nKT = K >> 6;

    for (int kt = 0; kt < nKT; ++kt) {
        int kbyte = kt*128;
        __syncthreads();
        #pragma unroll
        for (int i = 0; i < 4; ++i) {
            int row = srow + i*32;
            int dst = row*128 + ((sc8*16) ^ ssw);
            int rg = min(rb + row, R - 1);
            uint4 va = *(const uint4*)((const char*)X  + (size_t)rg*strideB + kbyte + sc8*16);
            uint4 vw = *(const uint4*)((const char*)WT + (size_t)(cb + row)*strideB + kbyte + sc8*16);
            *(uint4*)(smem + dst)         = va;
            *(uint4*)(smem + 16384 + dst) = vw;
        }
        __syncthreads();
        #pragma unroll
        for (int ks = 0; ks < 2; ++ks) {
            int kb = ks*64 + kb0;
            short8 ah[4], bv[4];
            #pragma unroll
            for (int i = 0; i < 4; ++i) {
                ah[i] = *(const short8*)(smem + aoff[i] + (kb ^ asw[i]));
                bv[i] = *(const short8*)(smem + boff[i] + (kb ^ bsw[i]));
            }
            #pragma unroll
            for (int mt = 0; mt < 4; ++mt)
                #pragma unroll
                for (int nt = 0; nt < 4; ++nt)
                    acc[mt][nt] = __builtin_amdgcn_mfma_f32_16x16x32_bf16(ah[mt], bv[nt], acc[mt][nt], 0, 0, 0);
        }
    }
    __syncthreads();
    constexpr int NSL = 128/C;
    constexpr int NHW = 64/C;
    int hg0 = cb / C;
    float asv[4], adv[4];
    #pragma unroll
    for (int nt = 0; nt < 4; ++nt) {
        int col = wc*64 + nt*16 + l15;
        int h = col / C, c = col - h*C;
        asv[nt] = as_[(hg0 + h)*C + c];
        adv[nt] = ad_[(hg0 + h)*C + c];
    }
    float* ebp = (float*)smem;               // [128][NSL][2]
    #pragma unroll
    for (int mt = 0; mt < 4; ++mt) {
        float ps[4][NHW] = {}, pd[4][NHW] = {};
        #pragma unroll
        for (int nt = 0; nt < 4; ++nt) {
            int sl = (nt*16)/C;
            #pragma unroll
            for (int q = 0; q < 4; ++q) {
                ps[q][sl] += acc[mt][nt][q]*asv[nt];
                pd[q][sl] += acc[mt][nt][q]*adv[nt];
            }
        }
        #pragma unroll
        for (int off = 1; off < 16; off <<= 1)
            #pragma unroll
            for (int q = 0; q < 4; ++q)
                #pragma unroll
                for (int sl = 0; sl < NHW; ++sl) {
                    ps[q][sl] += __shfl_xor(ps[q][sl], off);
                    pd[q][sl] += __shfl_xor(pd[q][sl], off);
                }
        if (l15 == 0) {
            #pragma unroll
            for (int q = 0; q < 4; ++q) {
                int row = wr*64 + mt*16 + lg*4 + q;
                #pragma unroll
                for (int sl = 0; sl < NHW; ++sl) {
                    ebp[(row*NSL + wc*NHW + sl)*2 + 0] = ps[q][sl];
                    ebp[(row*NSL + wc*NHW + sl)*2 + 1] = pd[q][sl];
                }
            }
        }
        #pragma unroll
        for (int nt = 0; nt < 4; ++nt) {
            int col = cb + wc*64 + nt*16 + l15;
            #pragma unroll
            for (int q = 0; q < 4; ++q) {
                int r = rb + wr*64 + mt*16 + lg*4 + q;
                if (r < R) Hout[(size_t)r*M + col] = rne(acc[mt][nt][q]);
            }
        }
    }
    __syncthreads();
    for (int i = tid; i < 128*NSL; i += 256) {
        int row = i / NSL, sl = i - row*NSL;
        int r = rb + row;
        if (r < R) {
            es[(size_t)r*8 + hg0 + sl] = ebp[i*2 + 0];
            ed[(size_t)r*8 + hg0 + sl] = ebp[i*2 + 1];
        }
    }
}

// Layer-4 linear: X[R,128](bf16) @ W4[128,8] + es/ed. 8 lanes/row, lane-split K.
__global__ __launch_bounds__(256) void k_lin4(
    const ushortT* __restrict__ X, const float* __restrict__ W,
    const float* __restrict__ as_, const float* __restrict__ ad_,
    float* __restrict__ Hout, float* __restrict__ es, float* __restrict__ ed, int R) {
    int tid = threadIdx.x;
    int l = tid & 7;
    int r = blockIdx.x*32 + (tid >> 3);
    if (r >= R) return;
    const ushortT* xp = X + (size_t)r*128 + l*16;
    uint4 a = *(const uint4*)xp;
    uint4 b = *(const uint4*)(xp + 8);
    float xv[16];
    xv[0]=bfl(a.x); xv[1]=bfh(a.x); xv[2]=bfl(a.y); xv[3]=bfh(a.y);
    xv[4]=bfl(a.z); xv[5]=bfh(a.z); xv[6]=bfl(a.w); xv[7]=bfh(a.w);
    xv[8]=bfl(b.x); xv[9]=bfh(b.x); xv[10]=bfl(b.y); xv[11]=bfh(b.y);
    xv[12]=bfl(b.z); xv[13]=bfh(b.z); xv[14]=bfl(b.w); xv[15]=bfh(b.w);
    float acc[8] = {};
    #pragma unroll
    for (int kk = 0; kk < 16; ++kk) {
        const float* wr = W + (l*16 + kk)*8;
        float4 wa = *(const float4*)wr, wb = *(const float4*)(wr + 4);
        acc[0] += xv[kk]*wa.x; acc[1] += xv[kk]*wa.y;
        acc[2] += xv[kk]*wa.z; acc[3] += xv[kk]*wa.w;
        acc[4] += xv[kk]*wb.x; acc[5] += xv[kk]*wb.y;
        acc[6] += xv[kk]*wb.z; acc[7] += xv[kk]*wb.w;
    }
    #pragma unroll
    for (int off = 4; off >= 1; off >>= 1)
        #pragma unroll
        for (int c = 0; c < 8; ++c) acc[c] += __shfl_xor(acc[c], off, 8);
    if (l == 0) {
        *(float4*)&Hout[(size_t)r*8]     = make_float4(acc[0],acc[1],acc[2],acc[3]);
        *(float4*)&Hout[(size_t)r*8 + 4] = make_float4(acc[4],acc[5],acc[6],acc[7]);
        float ps = 0.f, pd = 0.f;
        #pragma unroll
        for (int c = 0; c < 8; ++c) { ps += acc[c]*as_[c]; pd += acc[c]*ad_[c]; }
        es[r] = ps; ed[r] = pd;
    }
}

// Mean-pool per (t, graph): out4[R,8] -> emb[T,B,8]
__global__ void k_pool(const float* __restrict__ x4, float* __restrict__ emb, int t0) {
    __shared__ float red[256];
    int tl = blockIdx.x >> 3, b = blockIdx.x & 7;
    int tid = threadIdx.x;
    int c = tid & 7, nl = tid >> 3;
    float s = 0.f;
    for (int k = 0; k < 34; ++k) {
        int n = nl + 32*k;
        if (n < NPG) s += x4[((size_t)tl*NN + b*NPG + n)*8 + c];
    }
    red[tid] = s;
    __syncthreads();
    for (int st = 16; st >= 1; st >>= 1) {
        if (nl < st) red[tid] += red[tid + st*8];
        __syncthreads();
    }
    if (nl == 0) emb[((t0 + tl)*8 + b)*8 + c] = red[c] * (1.f/1080.f);
}

// LSTM (one block per batch element) + final FC. Register-resident w_hh row.
__global__ __launch_bounds__(512) void k_lstm(
    const float* __restrict__ emb, const float* __restrict__ w_ih,
    const float* __restrict__ w_hh, const float* __restrict__ b_ih,
    const float* __restrict__ b_hh, const float* __restrict__ w_fc,
    const float* __restrict__ b_fc, float* __restrict__ out) {
    int b = blockIdx.x, u = threadIdx.x;
    __shared__ float h[128], cst[128], g[512], eall[T_TOT*8];
    if (u < 128) { h[u] = 0.f; cst[u] = 0.f; }
    if (u < T_TOT*8) eall[u] = emb[((u >> 3)*8 + b)*8 + (u & 7)];
    float wreg[128];
    {
        const float* wp = w_hh + (size_t)u*128;
        #pragma unroll
        for (int k4 = 0; k4 < 32; ++k4) {
            float4 v = *(const float4*)&wp[k4*4];
            wreg[4*k4+0] = v.x; wreg[4*k4+1] = v.y;
            wreg[4*k4+2] = v.z; wreg[4*k4+3] = v.w;
        }
    }
    float wih[8];
    #pragma unroll
    for (int k = 0; k < 8; ++k) wih[k] = w_ih[(size_t)u*8 + k];
    float bsum = b_ih[u] + b_hh[u];
    __syncthreads();
    for (int t = 0; t < T_TOT; ++t) {
        float a0 = bsum, a1 = 0.f, a2 = 0.f, a3 = 0.f;
        #pragma unroll
        for (int k = 0; k < 8; ++k) a0 += eall[t*8 + k]*wih[k];
        #pragma unroll
        for (int k = 0; k < 32; ++k) {
            a0 += h[4*k+0]*wreg[4*k+0];
            a1 += h[4*k+1]*wreg[4*k+1];
            a2 += h[4*k+2]*wreg[4*k+2];
            a3 += h[4*k+3]*wreg[4*k+3];
        }
        g[u] = (a0 + a1) + (a2 + a3);
        __syncthreads();
        if (u < 128) {
            float ig = 1.f/(1.f + __expf(-g[u]));
            float fg = 1.f/(1.f + __expf(-g[128+u]));
            float gg = tanhf(g[256+u]);
            float og = 1.f/(1.f + __expf(-g[384+u]));
            float cn = fg*cst[u] + ig*gg;
            cst[u] = cn;
            h[u] = og*tanhf(cn);
        }
        __syncthreads();
    }
    if (u < 64) {
        float p0 = h[u]*w_fc[u]       + h[u+64]*w_fc[64+u];
        float p1 = h[u]*w_fc[128+u]   + h[u+64]*w_fc[192+u];
        #pragma unroll
        for (int off = 32; off >= 1; off >>= 1) {
            p0 += __shfl_xor(p0, off, 64);
            p1 += __shfl_xor(p1, off, 64);
        }
        if (u == 0) {
            out[b*2 + 0] = p0 + b_fc[0];
            out[b*2 + 1] = p1 + b_fc[1];
        }
    }
}

extern "C" void kernel_launch(void* const* d_in, const int* in_sizes, int n_in,
                              void* d_out, int out_size, void* d_ws, size_t ws_size,
                              hipStream_t stream) {
    const float* x_seq = (const float*)d_in[0];
    const int*   edge  = (const int*)d_in[1];   // row0 = src
    const float* W1 = (const float*)d_in[3];
    const float* as1 = (const float*)d_in[4];
    const float* ad1 = (const float*)d_in[5];
    const float* b1  = (const float*)d_in[6];
    const float* W2 = (const float*)d_in[7];
    const float* as2 = (const float*)d_in[8];
    const float* ad2 = (const float*)d_in[9];
    const float* b2  = (const float*)d_in[10];
    const float* W3 = (const float*)d_in[11];
    const float* as3 = (const float*)d_in[12];
    const float* ad3 = (const float*)d_in[13];
    const float* b3  = (const float*)d_in[14];
    const float* W4 = (const float*)d_in[15];
    const float* as4 = (const float*)d_in[16];
    const float* ad4 = (const float*)d_in[17];
    const float* b4  = (const float*)d_in[18];
    const float* w_ih = (const float*)d_in[19];
    const float* w_hh = (const float*)d_in[20];
    const float* b_ih = (const float*)d_in[21];
    const float* b_hh = (const float*)d_in[22];
    const float* w_fc = (const float*)d_in[23];
    const float* b_fc = (const float*)d_in[24];

    char* w = (char*)d_ws;
    auto alloc = [&](size_t bytes) {
        char* p = w; w += (bytes + 255) & ~(size_t)255; return p;
    };
    float*   A1  = (float*)alloc(128);
    float*   emb = (float*)alloc((size_t)T_TOT*8*8*4);
    ushortT* W2T = (ushortT*)alloc((size_t)256*512*2);
    ushortT* W3T = (ushortT*)alloc((size_t)128*256*2);
    size_t used = (size_t)(w - (char*)d_ws);
    // per-row bytes: Q 1024 + P 512 + G3 512 + H3 256 + G4 256 + 4 vecs x32
    size_t perT = (size_t)NN*(1024 + 512 + 512 + 256 + 256 + 128);
    size_t rem = (ws_size > used + 4096) ? ws_size - used - 4096 : 0;
    int Tc = (int)(rem / perT);
    if (Tc > T_TOT) Tc = T_TOT;
    if (Tc < 1) Tc = 1;
    ushortT* Q  = (ushortT*)alloc((size_t)Tc*NN*1024);
    ushortT* P  = (ushortT*)alloc((size_t)Tc*NN*512);
    ushortT* G3 = (ushortT*)alloc((size_t)Tc*NN*512);
    ushortT* H3 = (ushortT*)alloc((size_t)Tc*NN*256);
    ushortT* G4 = (ushortT*)alloc((size_t)Tc*NN*256);
    float*   ES = (float*)alloc((size_t)Tc*NN*32);
    float*   ED = (float*)alloc((size_t)Tc*NN*32);
    float*   P4 = (float*)alloc((size_t)Tc*NN*32);
    float*   G5 = (float*)alloc((size_t)Tc*NN*32);

    k_prep_l1<<<1, 64, 0, stream>>>(W1, as1, ad1, A1);
    k_prepW<<<(256*512 + 255)/256, 256, 0, stream>>>(W2, W2T, 512, 256);
    k_prepW<<<(128*256 + 255)/256, 256, 0, stream>>>(W3, W3T, 256, 128);

    for (int t0 = 0; t0 < T_TOT; t0 += Tc) {
        int tc = (Tc < T_TOT - t0) ? Tc : (T_TOT - t0);
        int R = tc*NN;
        int nrb = (R + 127)/128;
        const float* xoff = x_seq + (size_t)t0*NN*2;
        // Layer 1 (rank-2 + fused e-compute) -> bf16
        k_gat1<<<(R*8 + 31)/32, 256, 0, stream>>>(xoff, edge, A1, W1, b1, Q, R);
        // Layer 2: MFMA GEMM 512->256 (+es/ed), agg -> bf16
        k_gemm_mfma<32><<<dim3(nrb, 2), 256, 0, stream>>>(Q, W2T, as2, ad2, P, ES, ED, R, 512, 256);
        k_gat<8,32,4,true,true><<<(R*8 + 63)/64, 256, 0, stream>>>(P, edge, ES, ED, b2, nullptr, G3, R);
        // Layer 3: MFMA GEMM 256->128 (+es/ed), agg -> bf16
        k_gemm_mfma<16><<<dim3(nrb, 1), 256, 0, stream>>>(G3, W3T, as3, ad3, H3, ES, ED, R, 256, 128);
        k_gat<8,16,2,true,true><<<(R*8 + 127)/128, 256, 0, stream>>>(H3, edge, ES, ED, b3, nullptr, G4, R);
        // Layer 4: linear 128->8 (+es/ed), agg (fp32)
        k_lin4<<<(R + 31)/32, 256, 0, stream>>>(G4, W4, as4, ad4, P4, ES, ED, R);
        k_gat<1,8,2,false,false><<<(R + 127)/128, 256, 0, stream>>>(P4, edge, ES, ED, b4, G5, nullptr, R);
        // Pool
        k_pool<<<tc*8, 256, 0, stream>>>(G5, emb, t0);
    }
    k_lstm<<<8, 512, 0, stream>>>(emb, w_ih, w_hh, b_ih, b_hh, w_fc, b_fc, (float*)d_out);
}

// Round 8
// 397.064 us; speedup vs baseline: 3.9113x; 1.0089x over previous
//
#include <hip/hip_runtime.h>
#include <math.h>

#define T_TOT 10
#define NB    8
#define NPG   1080
#define NN    (NB*NPG)      // 8640 nodes
#define DEG   16

typedef unsigned short ushortT;
using short8 = __attribute__((ext_vector_type(8))) short;
using f32x4  = __attribute__((ext_vector_type(4))) float;

__device__ __forceinline__ float lrelu(float v) { return v > 0.f ? v : 0.2f*v; }
__device__ __forceinline__ float elu1(float v)  { return v > 0.f ? v : (__expf(v) - 1.f); }
__device__ __forceinline__ float bf2f(ushortT h){ return __uint_as_float(((unsigned)h) << 16); }
__device__ __forceinline__ float bfl(unsigned u){ return __uint_as_float(u << 16); }
__device__ __forceinline__ float bfh(unsigned u){ return __uint_as_float(u & 0xFFFF0000u); }
__device__ __forceinline__ ushortT rne(float v) {
    unsigned u = __float_as_uint(v);
    u += 0x7FFFu + ((u >> 16) & 1u);
    return (ushortT)(u >> 16);
}
__device__ __forceinline__ unsigned pk2(float a, float b) {
    return (unsigned)rne(a) | ((unsigned)rne(b) << 16);
}
// bijective XCD swizzle (8 XCDs): contiguous work range per XCD (L2 locality).
__device__ __forceinline__ int xswz(int b, int nwg) {
    int q = nwg >> 3, r = nwg & 7;
    int x = b & 7, i = b >> 3;
    return x*q + min(x, r) + i;
}
// async global->LDS 16B: wave-uniform LDS base + lane*16 (HW semantics).
// laneoff used only by the sync fallback.
__device__ __forceinline__ void gld16(const void* g, void* lbase, int laneoff) {
#if __has_builtin(__builtin_amdgcn_global_load_lds)
    typedef __attribute__((address_space(1))) const unsigned int GU;
    typedef __attribute__((address_space(3))) unsigned int LU;
    __builtin_amdgcn_global_load_lds((GU*)g, (LU*)lbase, 16, 0, 0);
    (void)laneoff;
#else
    *(uint4*)((char*)lbase + laneoff) = *(const uint4*)g;
#endif
}

// ---------------------------------------------------------------------------
// L1 precompute: A[sd][k][h] = dot(W1[k, h*64:(h+1)*64], att_{s,d}[h,:])
__global__ void k_prep_l1(const float* __restrict__ W1, const float* __restrict__ as1,
                          const float* __restrict__ ad1, float* __restrict__ A) {
    int tid = threadIdx.x;
    if (tid >= 32) return;
    int h = tid & 7, k = (tid >> 3) & 1, sd = tid >> 4;
    const float* att = sd ? ad1 : as1;
    float acc = 0.f;
    for (int c = 0; c < 64; ++c) acc += W1[k*512 + h*64 + c] * att[h*64 + c];
    A[sd*16 + k*8 + h] = acc;
}

// W [K,M] fp32 -> WT [M,K] bf16 (RNE)
__global__ void k_prepW(const float* __restrict__ W, ushortT* __restrict__ WT, int K, int M) {
    int i = blockIdx.x*256 + threadIdx.x;
    if (i >= K*M) return;
    int k = i / M, m = i - k*M;
    WT[(size_t)m*K + k] = rne(W[i]);
}

// Layer-1: fused e-compute (rank-2) + attention + aggregate + linear + ELU -> bf16.
// 8 lanes per (r,head); register softmax, shfl reductions, no LDS/barrier.
__global__ __launch_bounds__(256) void k_gat1(
    const float* __restrict__ x, const int* __restrict__ esrc,
    const float* __restrict__ A, const float* __restrict__ W1,
    const float* __restrict__ b1, ushortT* __restrict__ q, int R) {
    int tid = threadIdx.x;
    int g = xswz(blockIdx.x, gridDim.x)*32 + (tid >> 3);   // group = r*8 + hh
    int l = tid & 7;
    if (g >= R*8) g = R*8 - 1;
    int r = g >> 3, hh = g & 7;
    int t = r / NN, n = r - t*NN;
    float2 xr = *(const float2*)&x[2*r];
    float As0 = A[hh], As1 = A[8+hh];
    float edv = xr.x*A[16+hh] + xr.y*A[24+hh];
    float ev[3], xs0[3], xs1[3];
    float m = -1e30f;
    #pragma unroll
    for (int s = 0; s < 3; ++s) {
        int j = s*8 + l;
        if (j < 17) {
            int src = (j == 16) ? r : (t*NN + esrc[n*DEG + j]);
            float2 xs = *(const float2*)&x[2*src];
            xs0[s] = xs.x; xs1[s] = xs.y;
            float e = lrelu(xs.x*As0 + xs.y*As1 + edv);
            ev[s] = e; m = fmaxf(m, e);
        } else { ev[s] = -1e30f; xs0[s] = 0.f; xs1[s] = 0.f; }
    }
    #pragma unroll
    for (int off = 4; off >= 1; off >>= 1) m = fmaxf(m, __shfl_xor(m, off, 8));
    float den = 0.f, p0 = 0.f, p1 = 0.f;
    #pragma unroll
    for (int s = 0; s < 3; ++s) {
        float e2 = __expf(ev[s] - m);
        den += e2; p0 += e2*xs0[s]; p1 += e2*xs1[s];
    }
    #pragma unroll
    for (int off = 4; off >= 1; off >>= 1) {
        den += __shfl_xor(den, off, 8);
        p0  += __shfl_xor(p0,  off, 8);
        p1  += __shfl_xor(p1,  off, 8);
    }
    float inv = 1.f/(den + 1e-16f);
    float xa0 = p0*inv, xa1 = p1*inv;
    int col = hh*64 + l*8;
    float4 w0a = *(const float4*)&W1[col],       w0b = *(const float4*)&W1[col+4];
    float4 w1a = *(const float4*)&W1[512+col],   w1b = *(const float4*)&W1[512+col+4];
    float4 bba = *(const float4*)&b1[col],       bbb = *(const float4*)&b1[col+4];
    float v0 = elu1(xa0*w0a.x + xa1*w1a.x + bba.x);
    float v1 = elu1(xa0*w0a.y + xa1*w1a.y + bba.y);
    float v2 = elu1(xa0*w0a.z + xa1*w1a.z + bba.z);
    float v3 = elu1(xa0*w0a.w + xa1*w1a.w + bba.w);
    float v4 = elu1(xa0*w0b.x + xa1*w1b.x + bbb.x);
    float v5 = elu1(xa0*w0b.y + xa1*w1b.y + bbb.y);
    float v6 = elu1(xa0*w0b.z + xa1*w1b.z + bbb.z);
    float v7 = elu1(xa0*w0b.w + xa1*w1b.w + bbb.w);
    uint4 o;
    o.x = pk2(v0,v1); o.y = pk2(v2,v3); o.z = pk2(v4,v5); o.w = pk2(v6,v7);
    *(uint4*)&q[(size_t)r*512 + col] = o;
}

// Generic GAT attention+aggregate (+bias+ELU). Register softmax + shfl
// broadcast; no LDS, no barrier. BFIN: bf16 input (8 ch/lane, 16B gathers);
// else fp32 (4 ch/lane). BFOUT: bf16 output.
template<int H, int C, int LANES, bool BFIN, bool BFOUT>
__global__ __launch_bounds__(256) void k_gat(
    const void* __restrict__ hb_, const int* __restrict__ esrc,
    const float* __restrict__ es, const float* __restrict__ ed,
    const float* __restrict__ bias, float* __restrict__ out,
    ushortT* __restrict__ ohi, int R) {
    constexpr int CPL = C/LANES;                 // 8 (bf16) or 4 (fp32)
    constexpr int GPB = 256/LANES;
    constexpr int EPL = (17 + LANES - 1)/LANES;
    constexpr int HC = H*C;
    int tid = threadIdx.x;
    int l = tid & (LANES-1);
    int g = xswz(blockIdx.x, gridDim.x)*GPB + tid/LANES;   // group = r*H + hh
    if (g >= R*H) g = R*H - 1;
    int r = g / H, hh = g % H;
    int t = r / NN, n = r - t*NN;
    float edv = ed[(size_t)r*H + hh];
    float ev[EPL]; int sv[EPL];
    float m = -1e30f;
    #pragma unroll
    for (int s = 0; s < EPL; ++s) {
        int j = s*LANES + l;
        if (j < 17) {
            int src = (j == 16) ? r : (t*NN + esrc[n*DEG + j]);
            sv[s] = src;
            float e = lrelu(es[(size_t)src*H + hh] + edv);
            ev[s] = e; m = fmaxf(m, e);
        } else { ev[s] = -1e30f; sv[s] = r; }
    }
    #pragma unroll
    for (int off = LANES/2; off >= 1; off >>= 1) m = fmaxf(m, __shfl_xor(m, off, LANES));
    float den = 0.f;
    float wv[EPL];
    #pragma unroll
    for (int s = 0; s < EPL; ++s) {
        float e2 = __expf(ev[s] - m);
        wv[s] = e2; den += e2;
    }
    #pragma unroll
    for (int off = LANES/2; off >= 1; off >>= 1) den += __shfl_xor(den, off, LANES);
    float inv = 1.f/(den + 1e-16f);
    #pragma unroll
    for (int s = 0; s < EPL; ++s) wv[s] *= inv;

    int lb = (tid & 63) & ~(LANES-1);            // group's base lane (abs)
    float acc[CPL] = {};
    #pragma unroll
    for (int j = 0; j < 17; ++j) {
        float wj = __shfl(wv[j/LANES], lb + (j & (LANES-1)), 64);
        int   sj = __shfl(sv[j/LANES], lb + (j & (LANES-1)), 64);
        if constexpr (BFIN) {
            const ushortT* hp = (const ushortT*)hb_ + (size_t)sj*HC + hh*C + l*CPL;
            uint4 hv = *(const uint4*)hp;
            acc[0] += wj*bfl(hv.x); acc[1] += wj*bfh(hv.x);
            acc[2] += wj*bfl(hv.y); acc[3] += wj*bfh(hv.y);
            acc[4] += wj*bfl(hv.z); acc[5] += wj*bfh(hv.z);
            acc[6] += wj*bfl(hv.w); acc[7] += wj*bfh(hv.w);
        } else {
            const float* hp = (const float*)hb_ + (size_t)sj*HC + hh*C + l*CPL;
            float4 hv = *(const float4*)hp;
            acc[0] += wj*hv.x; acc[1] += wj*hv.y;
            acc[2] += wj*hv.z; acc[3] += wj*hv.w;
        }
    }
    int base = hh*C + l*CPL;
    #pragma unroll
    for (int c = 0; c < CPL; ++c) acc[c] = elu1(acc[c] + bias[base + c]);
    if constexpr (BFOUT) {
        uint4 o;
        o.x = pk2(acc[0],acc[1]); o.y = pk2(acc[2],acc[3]);
        o.z = pk2(acc[4],acc[5]); o.w = pk2(acc[6],acc[7]);
        *(uint4*)&ohi[(size_t)r*HC + base] = o;
    } else {
        *(float4*)&out[(size_t)r*HC + base] = make_float4(acc[0],acc[1],acc[2],acc[3]);
    }
}

// MFMA GEMM: Hout[R,M](bf16) = X[R,K](bf16) @ WT[M,K](bf16)^T.
// 128x128 tile, 4 waves 2x2, BK=64. Double-buffered LDS + async
// global_load_lds (linear dest, pre-swizzled source; rule #21), T3-minimum
// 2-phase: stage(next) issued before compute(cur), one barrier per K-step.
template<int C>
__global__ __launch_bounds__(256) void k_gemm_mfma(
    const ushortT* __restrict__ X, const ushortT* __restrict__ WT,
    const float* __restrict__ as_, const float* __restrict__ ad_,
    ushortT* __restrict__ Hout, float* __restrict__ es, float* __restrict__ ed,
    int R, int K, int M) {
    __shared__ __align__(16) char smem[65536];   // 2 x (A 16K | B 16K)
    int tid = threadIdx.x;
    int wid = tid >> 6, l = tid & 63;
    int l15 = l & 15, lg = l >> 4;
    int wr = wid >> 1, wc = wid & 1;
    int rb = blockIdx.x*128, cb = blockIdx.y*128;
    const size_t strideB = (size_t)K*2;
    const int nKT = K >> 6;

    f32x4 acc[4][4] = {};
    int aoff[4], asw[4], boff[4], bsw[4];
    #pragma unroll
    for (int i = 0; i < 4; ++i) {
        int ar = wr*64 + i*16 + l15;
        aoff[i] = ar*128; asw[i] = (ar & 7) << 4;
        int bc = wc*64 + i*16 + l15;
        boff[i] = 16384 + bc*128; bsw[i] = (bc & 7) << 4;
    }
    int kb0 = lg*16;
    int srowL = wid*8 + (l >> 3);                // wave-local staging row
    int scolb = (l & 7)*16;

    auto stage = [&](int buf, int kt) {
        int kbyte = kt*128;
        char* base = smem + (buf << 15);
        #pragma unroll
        for (int i = 0; i < 4; ++i) {
            int row = i*32 + srowL;
            int colb = scolb ^ ((row & 7) << 4);   // pre-swizzled source
            const char* sa = (const char*)X  + (size_t)min(rb + row, R - 1)*strideB + kbyte + colb;
            const char* sb = (const char*)WT + (size_t)(cb + row)*strideB + kbyte + colb;
            int dchunk = (i*32 + wid*8)*128;       // linear LDS dest (wave-uniform)
            gld16(sa, base + dchunk,         l*16);
            gld16(sb, base + 16384 + dchunk, l*16);
        }
    };

    stage(0, 0);
    __syncthreads();                             // implicit vmcnt(0) drain
    for (int kt = 0; kt < nKT; ++kt) {
        int cur = kt & 1;
        if (kt + 1 < nKT) stage(cur ^ 1, kt + 1);
        const char* bufp = smem + (cur << 15);
        #pragma unroll
        for (int ks = 0; ks < 2; ++ks) {
            int kb = ks*64 + kb0;
            short8 ah[4], bv[4];
            #pragma unroll
            for (int i = 0; i < 4; ++i) {
                ah[i] = *(const short8*)(bufp + aoff[i] + (kb ^ asw[i]));
                bv[i] = *(const short8*)(bufp + boff[i] + (kb ^ bsw[i]));
            }
            #pragma unroll
            for (int mt = 0; mt < 4; ++mt)
                #pragma unroll
                for (int nt = 0; nt < 4; ++nt)
                    acc[mt][nt] = __builtin_amdgcn_mfma_f32_16x16x32_bf16(ah[mt], bv[nt], acc[mt][nt], 0, 0, 0);
        }
        __syncthreads();                         // drains next-tile staging too
    }
    // epilogue: es/ed per head + bf16 store (all waves synced by loop barrier)
    constexpr int NSL = 128/C;
    constexpr int NHW = 64/C;
    int hg0 = cb / C;
    float asv[4], adv[4];
    #pragma unroll
    for (int nt = 0; nt < 4; ++nt) {
        int col = wc*64 + nt*16 + l15;
        int h = col / C, c = col - h*C;
        asv[nt] = as_[(hg0 + h)*C + c];
        adv[nt] = ad_[(hg0 + h)*C + c];
    }
    float* ebp = (float*)smem;               // [128][NSL][2]
    #pragma unroll
    for (int mt = 0; mt < 4; ++mt) {
        float ps[4][NHW] = {}, pd[4][NHW] = {};
        #pragma unroll
        for (int nt = 0; nt < 4; ++nt) {
            int sl = (nt*16)/C;
            #pragma unroll
            for (int q = 0; q < 4; ++q) {
                ps[q][sl] += acc[mt][nt][q]*asv[nt];
                pd[q][sl] += acc[mt][nt][q]*adv[nt];
            }
        }
        #pragma unroll
        for (int off = 1; off < 16; off <<= 1)
            #pragma unroll
            for (int q = 0; q < 4; ++q)
                #pragma unroll
                for (int sl = 0; sl < NHW; ++sl) {
                    ps[q][sl] += __shfl_xor(ps[q][sl], off);
                    pd[q][sl] += __shfl_xor(pd[q][sl], off);
                }
        if (l15 == 0) {
            #pragma unroll
            for (int q = 0; q < 4; ++q) {
                int row = wr*64 + mt*16 + lg*4 + q;
                #pragma unroll
                for (int sl = 0; sl < NHW; ++sl) {
                    ebp[(row*NSL + wc*NHW + sl)*2 + 0] = ps[q][sl];
                    ebp[(row*NSL + wc*NHW + sl)*2 + 1] = pd[q][sl];
                }
            }
        }
        #pragma unroll
        for (int nt = 0; nt < 4; ++nt) {
            int col = cb + wc*64 + nt*16 + l15;
            #pragma unroll
            for (int q = 0; q < 4; ++q) {
                int r = rb + wr*64 + mt*16 + lg*4 + q;
                if (r < R) Hout[(size_t)r*M + col] = rne(acc[mt][nt][q]);
            }
        }
    }
    __syncthreads();
    for (int i = tid; i < 128*NSL; i += 256) {
        int row = i / NSL, sl = i - row*NSL;
        int r = rb + row;
        if (r < R) {
            es[(size_t)r*8 + hg0 + sl] = ebp[i*2 + 0];
            ed[(size_t)r*8 + hg0 + sl] = ebp[i*2 + 1];
        }
    }
}

// Layer-4 linear: X[R,128](bf16) @ W4[128,8] + es/ed. 8 lanes/row, lane-split K.
__global__ __launch_bounds__(256) void k_lin4(
    const ushortT* __restrict__ X, const float* __restrict__ W,
    const float* __restrict__ as_, const float* __restrict__ ad_,
    float* __restrict__ Hout, float* __restrict__ es, float* __restrict__ ed, int R) {
    int tid = threadIdx.x;
    int l = tid & 7;
    int r = blockIdx.x*32 + (tid >> 3);
    if (r >= R) return;
    const ushortT* xp = X + (size_t)r*128 + l*16;
    uint4 a = *(const uint4*)xp;
    uint4 b = *(const uint4*)(xp + 8);
    float xv[16];
    xv[0]=bfl(a.x); xv[1]=bfh(a.x); xv[2]=bfl(a.y); xv[3]=bfh(a.y);
    xv[4]=bfl(a.z); xv[5]=bfh(a.z); xv[6]=bfl(a.w); xv[7]=bfh(a.w);
    xv[8]=bfl(b.x); xv[9]=bfh(b.x); xv[10]=bfl(b.y); xv[11]=bfh(b.y);
    xv[12]=bfl(b.z); xv[13]=bfh(b.z); xv[14]=bfl(b.w); xv[15]=bfh(b.w);
    float acc[8] = {};
    #pragma unroll
    for (int kk = 0; kk < 16; ++kk) {
        const float* wr = W + (l*16 + kk)*8;
        float4 wa = *(const float4*)wr, wb = *(const float4*)(wr + 4);
        acc[0] += xv[kk]*wa.x; acc[1] += xv[kk]*wa.y;
        acc[2] += xv[kk]*wa.z; acc[3] += xv[kk]*wa.w;
        acc[4] += xv[kk]*wb.x; acc[5] += xv[kk]*wb.y;
        acc[6] += xv[kk]*wb.z; acc[7] += xv[kk]*wb.w;
    }
    #pragma unroll
    for (int off = 4; off >= 1; off >>= 1)
        #pragma unroll
        for (int c = 0; c < 8; ++c) acc[c] += __shfl_xor(acc[c], off, 8);
    if (l == 0) {
        *(float4*)&Hout[(size_t)r*8]     = make_float4(acc[0],acc[1],acc[2],acc[3]);
        *(float4*)&Hout[(size_t)r*8 + 4] = make_float4(acc[4],acc[5],acc[6],acc[7]);
        float ps = 0.f, pd = 0.f;
        #pragma unroll
        for (int c = 0; c < 8; ++c) { ps += acc[c]*as_[c]; pd += acc[c]*ad_[c]; }
        es[r] = ps; ed[r] = pd;
    }
}

// Mean-pool per (t, graph): out4[R,8] -> emb[T,B,8]
__global__ void k_pool(const float* __restrict__ x4, float* __restrict__ emb, int t0) {
    __shared__ float red[256];
    int tl = blockIdx.x >> 3, b = blockIdx.x & 7;
    int tid = threadIdx.x;
    int c = tid & 7, nl = tid >> 3;
    float s = 0.f;
    for (int k = 0; k < 34; ++k) {
        int n = nl + 32*k;
        if (n < NPG) s += x4[((size_t)tl*NN + b*NPG + n)*8 + c];
    }
    red[tid] = s;
    __syncthreads();
    for (int st = 16; st >= 1; st >>= 1) {
        if (nl < st) red[tid] += red[tid + st*8];
        __syncthreads();
    }
    if (nl == 0) emb[((t0 + tl)*8 + b)*8 + c] = red[c] * (1.f/1080.f);
}

// LSTM (one block per batch element) + final FC. Register-resident w_hh row.
__global__ __launch_bounds__(512) void k_lstm(
    const float* __restrict__ emb, const float* __restrict__ w_ih,
    const float* __restrict__ w_hh, const float* __restrict__ b_ih,
    const float* __restrict__ b_hh, const float* __restrict__ w_fc,
    const float* __restrict__ b_fc, float* __restrict__ out) {
    int b = blockIdx.x, u = threadIdx.x;
    __shared__ float h[128], cst[128], g[512], eall[T_TOT*8];
    if (u < 128) { h[u] = 0.f; cst[u] = 0.f; }
    if (u < T_TOT*8) eall[u] = emb[((u >> 3)*8 + b)*8 + (u & 7)];
    float wreg[128];
    {
        const float* wp = w_hh + (size_t)u*128;
        #pragma unroll
        for (int k4 = 0; k4 < 32; ++k4) {
            float4 v = *(const float4*)&wp[k4*4];
            wreg[4*k4+0] = v.x; wreg[4*k4+1] = v.y;
            wreg[4*k4+2] = v.z; wreg[4*k4+3] = v.w;
        }
    }
    float wih[8];
    #pragma unroll
    for (int k = 0; k < 8; ++k) wih[k] = w_ih[(size_t)u*8 + k];
    float bsum = b_ih[u] + b_hh[u];
    __syncthreads();
    for (int t = 0; t < T_TOT; ++t) {
        float a0 = bsum, a1 = 0.f, a2 = 0.f, a3 = 0.f;
        #pragma unroll
        for (int k = 0; k < 8; ++k) a0 += eall[t*8 + k]*wih[k];
        #pragma unroll
        for (int k = 0; k < 32; ++k) {
            a0 += h[4*k+0]*wreg[4*k+0];
            a1 += h[4*k+1]*wreg[4*k+1];
            a2 += h[4*k+2]*wreg[4*k+2];
            a3 += h[4*k+3]*wreg[4*k+3];
        }
        g[u] = (a0 + a1) + (a2 + a3);
        __syncthreads();
        if (u < 128) {
            float ig = 1.f/(1.f + __expf(-g[u]));
            float fg = 1.f/(1.f + __expf(-g[128+u]));
            float gg = tanhf(g[256+u]);
            float og = 1.f/(1.f + __expf(-g[384+u]));
            float cn = fg*cst[u] + ig*gg;
            cst[u] = cn;
            h[u] = og*tanhf(cn);
        }
        __syncthreads();
    }
    if (u < 64) {
        float p0 = h[u]*w_fc[u]       + h[u+64]*w_fc[64+u];
        float p1 = h[u]*w_fc[128+u]   + h[u+64]*w_fc[192+u];
        #pragma unroll
        for (int off = 32; off >= 1; off >>= 1) {
            p0 += __shfl_xor(p0, off, 64);
            p1 += __shfl_xor(p1, off, 64);
        }
        if (u == 0) {
            out[b*2 + 0] = p0 + b_fc[0];
            out[b*2 + 1] = p1 + b_fc[1];
        }
    }
}

extern "C" void kernel_launch(void* const* d_in, const int* in_sizes, int n_in,
                              void* d_out, int out_size, void* d_ws, size_t ws_size,
                              hipStream_t stream) {
    const float* x_seq = (const float*)d_in[0];
    const int*   edge  = (const int*)d_in[1];   // row0 = src
    const float* W1 = (const float*)d_in[3];
    const float* as1 = (const float*)d_in[4];
    const float* ad1 = (const float*)d_in[5];
    const float* b1  = (const float*)d_in[6];
    const float* W2 = (const float*)d_in[7];
    const float* as2 = (const float*)d_in[8];
    const float* ad2 = (const float*)d_in[9];
    const float* b2  = (const float*)d_in[10];
    const float* W3 = (const float*)d_in[11];
    const float* as3 = (const float*)d_in[12];
    const float* ad3 = (const float*)d_in[13];
    const float* b3  = (const float*)d_in[14];
    const float* W4 = (const float*)d_in[15];
    const float* as4 = (const float*)d_in[16];
    const float* ad4 = (const float*)d_in[17];
    const float* b4  = (const float*)d_in[18];
    const float* w_ih = (const float*)d_in[19];
    const float* w_hh = (const float*)d_in[20];
    const float* b_ih = (const float*)d_in[21];
    const float* b_hh = (const float*)d_in[22];
    const float* w_fc = (const float*)d_in[23];
    const float* b_fc = (const float*)d_in[24];

    char* w = (char*)d_ws;
    auto alloc = [&](size_t bytes) {
        char* p = w; w += (bytes + 255) & ~(size_t)255; return p;
    };
    float*   A1  = (float*)alloc(128);
    float*   emb = (float*)alloc((size_t)T_TOT*8*8*4);
    ushortT* W2T = (ushortT*)alloc((size_t)256*512*2);
    ushortT* W3T = (ushortT*)alloc((size_t)128*256*2);
    size_t used = (size_t)(w - (char*)d_ws);
    // per-row bytes: Q 1024 + P 512 + G3 512 + H3 256 + G4 256 + 4 vecs x32
    size_t perT = (size_t)NN*(1024 + 512 + 512 + 256 + 256 + 128);
    size_t rem = (ws_size > used + 4096) ? ws_size - used - 4096 : 0;
    int Tc = (int)(rem / perT);
    if (Tc > T_TOT) Tc = T_TOT;
    if (Tc < 1) Tc = 1;
    ushortT* Q  = (ushortT*)alloc((size_t)Tc*NN*1024);
    ushortT* P  = (ushortT*)alloc((size_t)Tc*NN*512);
    ushortT* G3 = (ushortT*)alloc((size_t)Tc*NN*512);
    ushortT* H3 = (ushortT*)alloc((size_t)Tc*NN*256);
    ushortT* G4 = (ushortT*)alloc((size_t)Tc*NN*256);
    float*   ES = (float*)alloc((size_t)Tc*NN*32);
    float*   ED = (float*)alloc((size_t)Tc*NN*32);
    float*   P4 = (float*)alloc((size_t)Tc*NN*32);
    float*   G5 = (float*)alloc((size_t)Tc*NN*32);

    k_prep_l1<<<1, 64, 0, stream>>>(W1, as1, ad1, A1);
    k_prepW<<<(256*512 + 255)/256, 256, 0, stream>>>(W2, W2T, 512, 256);
    k_prepW<<<(128*256 + 255)/256, 256, 0, stream>>>(W3, W3T, 256, 128);

    for (int t0 = 0; t0 < T_TOT; t0 += Tc) {
        int tc = (Tc < T_TOT - t0) ? Tc : (T_TOT - t0);
        int R = tc*NN;
        int nrb = (R + 127)/128;
        const float* xoff = x_seq + (size_t)t0*NN*2;
        // Layer 1 (rank-2 + fused e-compute) -> bf16
        k_gat1<<<(R*8 + 31)/32, 256, 0, stream>>>(xoff, edge, A1, W1, b1, Q, R);
        // Layer 2: MFMA GEMM 512->256 (+es/ed), agg -> bf16
        k_gemm_mfma<32><<<dim3(nrb, 2), 256, 0, stream>>>(Q, W2T, as2, ad2, P, ES, ED, R, 512, 256);
        k_gat<8,32,4,true,true><<<(R*8 + 63)/64, 256, 0, stream>>>(P, edge, ES, ED, b2, nullptr, G3, R);
        // Layer 3: MFMA GEMM 256->128 (+es/ed), agg -> bf16
        k_gemm_mfma<16><<<dim3(nrb, 1), 256, 0, stream>>>(G3, W3T, as3, ad3, H3, ES, ED, R, 256, 128);
        k_gat<8,16,2,true,true><<<(R*8 + 127)/128, 256, 0, stream>>>(H3, edge, ES, ED, b3, nullptr, G4, R);
        // Layer 4: linear 128->8 (+es/ed), agg (fp32)
        k_lin4<<<(R + 31)/32, 256, 0, stream>>>(G4, W4, as4, ad4, P4, ES, ED, R);
        k_gat<1,8,2,false,false><<<(R + 127)/128, 256, 0, stream>>>(P4, edge, ES, ED, b4, G5, nullptr, R);
        // Pool
        k_pool<<<tc*8, 256, 0, stream>>>(G5, emb, t0);
    }
    k_lstm<<<8, 512, 0, stream>>>(emb, w_ih, w_hh, b_ih, b_hh, w_fc, b_fc, (float*)d_out);
}